// Round 1
// baseline (1108.868 us; speedup 1.0000x reference)
//
#include <hip/hip_runtime.h>
#include <hip/hip_bf16.h>

#define NN 30000
#define FI 16
#define EE 300000
#define ETOT (EE + NN)
#define HD 256
#define NH 8
#define CH 32
#define NL 3
#define SS 256
#define KS 128
#define NHC 4
#define HC 64

// ---------------- pre-transform: H = x @ pre_W + pre_b ----------------
__global__ __launch_bounds__(256) void k_pre(const float* __restrict__ x,
    const float* __restrict__ W, const float* __restrict__ b,
    float* __restrict__ H)
{
  __shared__ float xr[FI];
  int r = blockIdx.x;
  int j = threadIdx.x;
  if (j < FI) xr[j] = x[r * FI + j];
  __syncthreads();
  float acc = b[j];
#pragma unroll
  for (int k = 0; k < FI; ++k) acc += xr[k] * W[k * HD + j];
  H[r * HD + j] = acc;
}

// ---------------- CSR build ----------------
__global__ __launch_bounds__(256) void k_count(const int* __restrict__ ei, int* __restrict__ cnt)
{
  int i = blockIdx.x * 256 + threadIdx.x;
  if (i >= ETOT) return;
  int dst = (i < EE) ? ei[EE + i] : (i - EE);
  atomicAdd(&cnt[dst], 1);
}

__global__ __launch_bounds__(1024) void k_scan(const int* __restrict__ cnt,
    int* __restrict__ rowptr, int* __restrict__ wptr)
{
  __shared__ int buf[1024];
  __shared__ int carry_s;
  if (threadIdx.x == 0) carry_s = 0;
  __syncthreads();
  for (int base = 0; base < NN; base += 1024) {
    int i = base + threadIdx.x;
    int v = (i < NN) ? cnt[i] : 0;
    buf[threadIdx.x] = v;
    __syncthreads();
    for (int st = 1; st < 1024; st <<= 1) {
      int t = (threadIdx.x >= st) ? buf[threadIdx.x - st] : 0;
      __syncthreads();
      buf[threadIdx.x] += t;
      __syncthreads();
    }
    int excl = carry_s + buf[threadIdx.x] - v;
    if (i < NN) { rowptr[i] = excl; wptr[i] = excl; }
    __syncthreads();
    if (threadIdx.x == 1023) carry_s += buf[1023];
    __syncthreads();
  }
  if (threadIdx.x == 0) rowptr[NN] = carry_s;
}

__global__ __launch_bounds__(256) void k_scatter(const int* __restrict__ ei,
    int* __restrict__ wptr, int* __restrict__ csr_src, int* __restrict__ csr_eid)
{
  int i = blockIdx.x * 256 + threadIdx.x;
  if (i >= ETOT) return;
  int src = (i < EE) ? ei[i] : (i - EE);
  int dst = (i < EE) ? ei[EE + i] : (i - EE);
  int pos = atomicAdd(&wptr[dst], 1);
  csr_src[pos] = src;
  csr_eid[pos] = i;
}

// ---------------- fused xl/xr GEMM: [NN,256] @ [256,256] x2 ----------------
// grid.x = ceil(NN/64), grid.y = 8 (col tiles over the 512 virtual columns)
__global__ __launch_bounds__(256) void k_gemm(const float* __restrict__ A,
    const float* __restrict__ Wl, const float* __restrict__ Wr,
    float* __restrict__ Xl, float* __restrict__ Xr)
{
  __shared__ float As[16][64 + 4];
  __shared__ float Bs[16][64 + 4];
  int jt = blockIdx.y * 64;
  const float* W;
  float* Out;
  int j0;
  if (jt < HD) { W = Wl; Out = Xl; j0 = jt; }
  else { W = Wr; Out = Xr; j0 = jt - HD; }
  int row0 = blockIdx.x * 64;
  int t = threadIdx.x;
  int tx = t & 15, ty = t >> 4;
  float acc[4][4] = {};
  int lr = t >> 2;           // row within A tile
  int lk = (t & 3) * 4;      // k offset (float4)
  int wk = t >> 4;           // k within W tile
  int wn = (t & 15) * 4;     // n offset
  for (int k0 = 0; k0 < HD; k0 += 16) {
    int ar = row0 + lr;
    float4 av = make_float4(0.f, 0.f, 0.f, 0.f);
    if (ar < NN) av = *(const float4*)(A + ar * HD + k0 + lk);
    As[lk + 0][lr] = av.x; As[lk + 1][lr] = av.y;
    As[lk + 2][lr] = av.z; As[lk + 3][lr] = av.w;
    float4 wv = *(const float4*)(W + (k0 + wk) * HD + j0 + wn);
    Bs[wk][wn + 0] = wv.x; Bs[wk][wn + 1] = wv.y;
    Bs[wk][wn + 2] = wv.z; Bs[wk][wn + 3] = wv.w;
    __syncthreads();
#pragma unroll
    for (int k = 0; k < 16; ++k) {
      float4 a = *(const float4*)&As[k][ty * 4];
      float4 bb = *(const float4*)&Bs[k][tx * 4];
      acc[0][0] += a.x * bb.x; acc[0][1] += a.x * bb.y; acc[0][2] += a.x * bb.z; acc[0][3] += a.x * bb.w;
      acc[1][0] += a.y * bb.x; acc[1][1] += a.y * bb.y; acc[1][2] += a.y * bb.z; acc[1][3] += a.y * bb.w;
      acc[2][0] += a.z * bb.x; acc[2][1] += a.z * bb.y; acc[2][2] += a.z * bb.z; acc[2][3] += a.z * bb.w;
      acc[3][0] += a.w * bb.x; acc[3][1] += a.w * bb.y; acc[3][2] += a.w * bb.z; acc[3][3] += a.w * bb.w;
    }
    __syncthreads();
  }
#pragma unroll
  for (int i = 0; i < 4; ++i) {
    int r = row0 + ty * 4 + i;
    if (r < NN) {
      float4 o = make_float4(acc[i][0], acc[i][1], acc[i][2], acc[i][3]);
      *(float4*)(Out + r * HD + j0 + tx * 4) = o;
    }
  }
}

// ---------------- per-edge attention logits: e[edge][head] ----------------
// one wave per edge; lane handles 4 channels (head = lane>>3)
__global__ __launch_bounds__(256) void k_edge(const float* __restrict__ Xl,
    const float* __restrict__ Xr, const float* __restrict__ attw,
    const int* __restrict__ ei, float* __restrict__ ebuf)
{
  int widx = (blockIdx.x * 256 + threadIdx.x) >> 6;
  int lane = threadIdx.x & 63;
  if (widx >= ETOT) return;
  int srcn = (widx < EE) ? ei[widx] : (widx - EE);
  int dstn = (widx < EE) ? ei[EE + widx] : (widx - EE);
  int c = lane * 4;
  float4 a = *(const float4*)(Xl + (size_t)srcn * HD + c);
  float4 b = *(const float4*)(Xr + (size_t)dstn * HD + c);
  float4 w = *(const float4*)(attw + c);
  float m, p = 0.f;
  m = a.x + b.x; m = (m > 0.f) ? m : 0.2f * m; p += w.x * m;
  m = a.y + b.y; m = (m > 0.f) ? m : 0.2f * m; p += w.y * m;
  m = a.z + b.z; m = (m > 0.f) ? m : 0.2f * m; p += w.z * m;
  m = a.w + b.w; m = (m > 0.f) ? m : 0.2f * m; p += w.w * m;
  p += __shfl_xor(p, 1);
  p += __shfl_xor(p, 2);
  p += __shfl_xor(p, 4);
  if ((lane & 7) == 0) ebuf[(size_t)widx * NH + (lane >> 3)] = p;
}

// ---------------- per-node softmax + aggregation ----------------
// one wave per node; block = 256 (4 nodes)
__global__ __launch_bounds__(256) void k_agg(const float* __restrict__ Xl,
    const float* __restrict__ ebuf, const int* __restrict__ rowptr,
    const int* __restrict__ csr_src, const int* __restrict__ csr_eid,
    const float* __restrict__ bias, float* __restrict__ Hout)
{
  int node = blockIdx.x * 4 + (threadIdx.x >> 6);
  int lane = threadIdx.x & 63;
  if (node >= NN) return;
  int st = rowptr[node], en = rowptr[node + 1];
  int h8 = lane & 7;
  int slot = lane >> 3;
  float mx = -1e30f;
  for (int i = st + slot; i < en; i += 8)
    mx = fmaxf(mx, ebuf[(size_t)csr_eid[i] * NH + h8]);
  mx = fmaxf(mx, __shfl_xor(mx, 8));
  mx = fmaxf(mx, __shfl_xor(mx, 16));
  mx = fmaxf(mx, __shfl_xor(mx, 32));
  float dn = 0.f;
  for (int i = st + slot; i < en; i += 8)
    dn += expf(ebuf[(size_t)csr_eid[i] * NH + h8] - mx);
  dn += __shfl_xor(dn, 8);
  dn += __shfl_xor(dn, 16);
  dn += __shfl_xor(dn, 32);
  int hh = lane >> 3;
  float mh = __shfl(mx, hh, 64);
  float dh = __shfl(dn, hh, 64) + 1e-16f;
  float inv = 1.f / dh;
  int c = lane * 4;
  float a0 = 0.f, a1 = 0.f, a2 = 0.f, a3 = 0.f;
  for (int i = st; i < en; ++i) {
    float al = expf(ebuf[(size_t)csr_eid[i] * NH + hh] - mh) * inv;
    float4 v = *(const float4*)(Xl + (size_t)csr_src[i] * HD + c);
    a0 += al * v.x; a1 += al * v.y; a2 += al * v.z; a3 += al * v.w;
  }
  float4 bb = *(const float4*)(bias + c);
  float o0 = a0 + bb.x, o1 = a1 + bb.y, o2 = a2 + bb.z, o3 = a3 + bb.w;
  o0 = (o0 > 0.f) ? o0 : expm1f(o0);
  o1 = (o1 > 0.f) ? o1 : expm1f(o1);
  o2 = (o2 > 0.f) ? o2 : expm1f(o2);
  o3 = (o3 > 0.f) ? o3 : expm1f(o3);
  *(float4*)(Hout + (size_t)node * HD + c) = make_float4(o0, o1, o2, o3);
}

// ---------------- global mean ----------------
__global__ __launch_bounds__(256) void k_gsum(const float* __restrict__ H,
    const int* __restrict__ batch, float* __restrict__ gsum, int* __restrict__ gcnt)
{
  int r0 = blockIdx.x * 128;
  int rend = r0 + 128; if (rend > NN) rend = NN;
  int c = threadIdx.x;
  float acc = 0.f; int cn = 0;
  for (int r = r0; r < rend; ++r) {
    if (batch[r] == 0) { acc += H[(size_t)r * HD + c]; cn++; }
  }
  atomicAdd(&gsum[c], acc);
  if (c == 0) atomicAdd(gcnt, cn);
}

__global__ __launch_bounds__(256) void k_gfin(const float* __restrict__ gsum,
    const int* __restrict__ gcnt, float* __restrict__ gvec)
{
  gvec[threadIdx.x] = gsum[threadIdx.x] / (float)(*gcnt);
}

// ---------------- sheet gather + mean ----------------
__global__ __launch_bounds__(256) void k_sheet(const float* __restrict__ H,
    const int* __restrict__ idx, float* __restrict__ sheet)
{
  int s = blockIdx.x, c = threadIdx.x;
  float acc = 0.f;
  for (int k = 0; k < KS; ++k) {
    int n = idx[s * KS + k];
    acc += H[(size_t)n * HD + c];
  }
  sheet[s * HD + c] = acc * (1.f / KS);
}

// ---------------- generic row-MLP: Y = act(LN(X @ W + b)) ----------------
template <int KD, int OD, bool LN, bool RELU>
__global__ __launch_bounds__(OD) void k_rowmlp(const float* __restrict__ X,
    const float* __restrict__ W, const float* __restrict__ B,
    const float* __restrict__ G, const float* __restrict__ Be,
    float* __restrict__ Y)
{
  __shared__ float xr[KD];
  __shared__ float red[OD];
  int row = blockIdx.x;
  for (int k = threadIdx.x; k < KD; k += OD) xr[k] = X[row * KD + k];
  __syncthreads();
  int j = threadIdx.x;
  float acc = B[j];
#pragma unroll 8
  for (int k = 0; k < KD; ++k) acc += xr[k] * W[k * OD + j];
  if (LN) {
    red[j] = acc; __syncthreads();
    for (int s = OD / 2; s > 0; s >>= 1) { if (j < s) red[j] += red[j + s]; __syncthreads(); }
    float mu = red[0] * (1.f / OD);
    __syncthreads();
    float d = acc - mu;
    red[j] = d * d; __syncthreads();
    for (int s = OD / 2; s > 0; s >>= 1) { if (j < s) red[j] += red[j + s]; __syncthreads(); }
    float var = red[0] * (1.f / OD);
    acc = d * rsqrtf(var + 1e-5f) * G[j] + Be[j];
  }
  if (RELU) acc = fmaxf(acc, 0.f);
  Y[row * OD + j] = acc;
}

// ---------------- cross-attention scores + softmax ----------------
__global__ __launch_bounds__(256) void k_caatt(const float* __restrict__ Q,
    const float* __restrict__ Km, float* __restrict__ att)
{
  int q = blockIdx.x, h = blockIdx.y;
  __shared__ float qv[HC];
  __shared__ float red[256];
  int t = threadIdx.x;
  if (t < HC) qv[t] = Q[q * HD + h * HC + t];
  __syncthreads();
  const float* kr = Km + t * HD + h * HC;
  float s = 0.f;
#pragma unroll 8
  for (int d = 0; d < HC; ++d) s += qv[d] * kr[d];
  s *= 0.125f;  // 1/sqrt(64)
  red[t] = s; __syncthreads();
  for (int st = 128; st > 0; st >>= 1) { if (t < st) red[t] = fmaxf(red[t], red[t + st]); __syncthreads(); }
  float mx = red[0]; __syncthreads();
  float ev = expf(s - mx);
  red[t] = ev; __syncthreads();
  for (int st = 128; st > 0; st >>= 1) { if (t < st) red[t] += red[t + st]; __syncthreads(); }
  att[((size_t)h * SS + q) * SS + t] = ev / red[0];
}

// ---------------- att @ V ----------------
__global__ __launch_bounds__(256) void k_capply(const float* __restrict__ att,
    const float* __restrict__ V, float* __restrict__ out)
{
  __shared__ float aw[NHC * SS];
  int q = blockIdx.x;
  for (int i = threadIdx.x; i < NHC * SS; i += 256) {
    int h = i >> 8, k = i & 255;
    aw[i] = att[((size_t)h * SS + q) * SS + k];
  }
  __syncthreads();
  int c = threadIdx.x, h = c >> 6;
  float acc = 0.f;
  for (int k = 0; k < SS; ++k) acc += aw[h * SS + k] * V[k * HD + c];
  out[q * HD + c] = acc;
}

// ---------------- concat [fused | g] ----------------
__global__ __launch_bounds__(256) void k_concat(const float* __restrict__ fused,
    const float* __restrict__ gvec, float* __restrict__ hqin)
{
  int s = blockIdx.x, t = threadIdx.x;
  hqin[s * 512 + t] = fused[s * HD + t];
  hqin[s * 512 + 256 + t] = gvec[t];
}

// ---------------- q_values: hq2 @ W3 + b3 ----------------
__global__ __launch_bounds__(128) void k_qval(const float* __restrict__ hq2,
    const float* __restrict__ W3, const float* __restrict__ b3, float* __restrict__ out)
{
  int s = blockIdx.x, j = threadIdx.x;
  __shared__ float red[128];
  red[j] = hq2[s * 128 + j] * W3[j];
  __syncthreads();
  for (int st = 64; st > 0; st >>= 1) { if (j < st) red[j] += red[j + st]; __syncthreads(); }
  if (j == 0) out[s] = red[0] + b3[0];
}

// ---------------- done predictor (single block) ----------------
__global__ __launch_bounds__(128) void k_done(const float* __restrict__ gvec,
    const float* __restrict__ W1, const float* __restrict__ b1,
    const float* __restrict__ g1, const float* __restrict__ be1,
    const float* __restrict__ W2, const float* __restrict__ b2,
    float* __restrict__ out)
{
  __shared__ float gl[256];
  __shared__ float red[128];
  int j = threadIdx.x;
  gl[j] = gvec[j]; gl[j + 128] = gvec[j + 128];
  __syncthreads();
  float acc = b1[j];
  for (int k = 0; k < 256; ++k) acc += gl[k] * W1[k * 128 + j];
  red[j] = acc; __syncthreads();
  for (int st = 64; st > 0; st >>= 1) { if (j < st) red[j] += red[j + st]; __syncthreads(); }
  float mu = red[0] * (1.f / 128.f); __syncthreads();
  float d = acc - mu;
  red[j] = d * d; __syncthreads();
  for (int st = 64; st > 0; st >>= 1) { if (j < st) red[j] += red[j + st]; __syncthreads(); }
  float var = red[0] * (1.f / 128.f);
  float hd = fmaxf(d * rsqrtf(var + 1e-5f) * g1[j] + be1[j], 0.f);
  __syncthreads();
  red[j] = hd * W2[j]; __syncthreads();
  for (int st = 64; st > 0; st >>= 1) { if (j < st) red[j] += red[j + st]; __syncthreads(); }
  if (j == 0) out[0] = red[0] + b2[0];
}

// =====================================================================
extern "C" void kernel_launch(void* const* d_in, const int* in_sizes, int n_in,
                              void* d_out, int out_size, void* d_ws, size_t ws_size,
                              hipStream_t stream) {
  const float* x      = (const float*)d_in[0];
  const int*   ei     = (const int*)d_in[1];
  const int*   batch  = (const int*)d_in[2];
  const int*   sheet_idx = (const int*)d_in[3];
  const float* sheet_feat = (const float*)d_in[4];
  const float* pre_W  = (const float*)d_in[5];
  const float* pre_b  = (const float*)d_in[6];
  const float* gat_Wl = (const float*)d_in[7];
  const float* gat_Wr = (const float*)d_in[8];
  const float* gat_att = (const float*)d_in[9];
  const float* gat_b  = (const float*)d_in[10];
  const float* geo_W1 = (const float*)d_in[11];
  const float* geo_b1 = (const float*)d_in[12];
  const float* geo_g1 = (const float*)d_in[13];
  const float* geo_be1 = (const float*)d_in[14];
  const float* geo_W2 = (const float*)d_in[15];
  const float* geo_b2 = (const float*)d_in[16];
  const float* geo_g2 = (const float*)d_in[17];
  const float* geo_be2 = (const float*)d_in[18];
  const float* ca_Wq = (const float*)d_in[19];
  const float* ca_bq = (const float*)d_in[20];
  const float* ca_Wk = (const float*)d_in[21];
  const float* ca_bk = (const float*)d_in[22];
  const float* ca_Wv = (const float*)d_in[23];
  const float* ca_bv = (const float*)d_in[24];
  const float* ca_Wo = (const float*)d_in[25];
  const float* ca_bo = (const float*)d_in[26];
  const float* q_W1 = (const float*)d_in[27];
  const float* q_b1 = (const float*)d_in[28];
  const float* q_g1 = (const float*)d_in[29];
  const float* q_be1 = (const float*)d_in[30];
  const float* q_W2 = (const float*)d_in[31];
  const float* q_b2 = (const float*)d_in[32];
  const float* q_g2 = (const float*)d_in[33];
  const float* q_be2 = (const float*)d_in[34];
  const float* q_W3 = (const float*)d_in[35];
  const float* q_b3 = (const float*)d_in[36];
  const float* d_W1 = (const float*)d_in[37];
  const float* d_b1 = (const float*)d_in[38];
  const float* d_g1 = (const float*)d_in[39];
  const float* d_be1 = (const float*)d_in[40];
  const float* d_W2 = (const float*)d_in[41];
  const float* d_b2 = (const float*)d_in[42];

  float* ws = (float*)d_ws;
  size_t o = 0;
  float* bufA = ws + o; o += (size_t)NN * HD;
  float* bufB = ws + o; o += (size_t)NN * HD;
  float* bufC = ws + o; o += (size_t)NN * HD;
  float* ebuf = ws + o; o += (size_t)ETOT * NH;
  float* gsum = ws + o; o += 256;
  float* gvec = ws + o; o += 256;
  float* sheetb = ws + o; o += SS * HD;
  float* geo1b = ws + o; o += SS * HD;
  float* geo2b = ws + o; o += SS * HD;
  float* qb = ws + o; o += SS * HD;
  float* kb = ws + o; o += SS * HD;
  float* vb = ws + o; o += SS * HD;
  float* attb = ws + o; o += (size_t)NHC * SS * SS;
  float* pvb = ws + o; o += SS * HD;
  float* fusedb = ws + o; o += SS * HD;
  float* hqin = ws + o; o += SS * 512;
  float* hq1b = ws + o; o += SS * HD;
  float* hq2b = ws + o; o += SS * 128;
  int* ip = (int*)(ws + o);
  int* cnt = ip; ip += NN;
  int* rowptr = ip; ip += NN + 1;
  int* wptr = ip; ip += NN;
  int* csr_src = ip; ip += ETOT;
  int* csr_eid = ip; ip += ETOT;
  int* gcnt = ip; ip += 1;

  float* out_q = (float*)d_out;        // [256]
  float* out_d = out_q + SS;           // [1]

  // zero counters
  hipMemsetAsync(cnt, 0, (size_t)NN * sizeof(int), stream);
  hipMemsetAsync(gsum, 0, 256 * sizeof(float), stream);
  hipMemsetAsync(gcnt, 0, sizeof(int), stream);

  // CSR build
  k_count<<<(ETOT + 255) / 256, 256, 0, stream>>>(ei, cnt);
  k_scan<<<1, 1024, 0, stream>>>(cnt, rowptr, wptr);
  k_scatter<<<(ETOT + 255) / 256, 256, 0, stream>>>(ei, wptr, csr_src, csr_eid);

  // pre-transform
  k_pre<<<NN, 256, 0, stream>>>(x, pre_W, pre_b, bufA);

  // GAT layers
  dim3 ggrid((NN + 63) / 64, 8);
  for (int l = 0; l < NL; ++l) {
    k_gemm<<<ggrid, 256, 0, stream>>>(bufA, gat_Wl + (size_t)l * HD * HD,
                                      gat_Wr + (size_t)l * HD * HD, bufB, bufC);
    k_edge<<<(ETOT + 3) / 4, 256, 0, stream>>>(bufB, bufC, gat_att + l * NH * CH, ei, ebuf);
    k_agg<<<(NN + 3) / 4, 256, 0, stream>>>(bufB, ebuf, rowptr, csr_src, csr_eid,
                                            gat_b + l * HD, bufA);
  }

  // global mean
  k_gsum<<<(NN + 127) / 128, 256, 0, stream>>>(bufA, batch, gsum, gcnt);
  k_gfin<<<1, 256, 0, stream>>>(gsum, gcnt, gvec);

  // sheet pooling
  k_sheet<<<SS, 256, 0, stream>>>(bufA, sheet_idx, sheetb);

  // geometry encoder
  k_rowmlp<16, 256, true, true><<<SS, 256, 0, stream>>>(sheet_feat, geo_W1, geo_b1, geo_g1, geo_be1, geo1b);
  k_rowmlp<256, 256, true, true><<<SS, 256, 0, stream>>>(geo1b, geo_W2, geo_b2, geo_g2, geo_be2, geo2b);

  // cross attention
  k_rowmlp<256, 256, false, false><<<SS, 256, 0, stream>>>(sheetb, ca_Wq, ca_bq, nullptr, nullptr, qb);
  k_rowmlp<256, 256, false, false><<<SS, 256, 0, stream>>>(geo2b, ca_Wk, ca_bk, nullptr, nullptr, kb);
  k_rowmlp<256, 256, false, false><<<SS, 256, 0, stream>>>(geo2b, ca_Wv, ca_bv, nullptr, nullptr, vb);
  dim3 agrid(SS, NHC);
  k_caatt<<<agrid, 256, 0, stream>>>(qb, kb, attb);
  k_capply<<<SS, 256, 0, stream>>>(attb, vb, pvb);
  k_rowmlp<256, 256, false, false><<<SS, 256, 0, stream>>>(pvb, ca_Wo, ca_bo, nullptr, nullptr, fusedb);

  // q-MLP
  k_concat<<<SS, 256, 0, stream>>>(fusedb, gvec, hqin);
  k_rowmlp<512, 256, true, true><<<SS, 256, 0, stream>>>(hqin, q_W1, q_b1, q_g1, q_be1, hq1b);
  k_rowmlp<256, 128, true, true><<<SS, 128, 0, stream>>>(hq1b, q_W2, q_b2, q_g2, q_be2, hq2b);
  k_qval<<<SS, 128, 0, stream>>>(hq2b, q_W3, q_b3, out_q);

  // done predictor
  k_done<<<1, 128, 0, stream>>>(gvec, d_W1, d_b1, d_g1, d_be1, d_W2, d_b2, out_d);
}

// Round 2
// 496.395 us; speedup vs baseline: 2.2338x; 2.2338x over previous
//
#include <hip/hip_runtime.h>
#include <hip/hip_bf16.h>
#include <stdint.h>

#define NN 30000
#define MPAD 30080
#define FI 16
#define EE 300000
#define ETOT (EE + NN)
#define HD 256
#define NH 8
#define CH 32
#define NL 3
#define SS 256
#define KS 128
#define NHC 4
#define HC 64

typedef _Float16 half8 __attribute__((ext_vector_type(8)));
typedef _Float16 half4v __attribute__((ext_vector_type(4)));
typedef float f32x4 __attribute__((ext_vector_type(4)));

// ---------------- weight transpose+convert: WT[m][n][k] = W_m[k][n] ----------------
__global__ __launch_bounds__(256) void k_wconv(const float* __restrict__ Wl,
    const float* __restrict__ Wr, _Float16* __restrict__ WT)
{
  int m = blockIdx.x >> 8;       // 0..5 : l*2 + (0=Wl,1=Wr)
  int n = blockIdx.x & 255;
  int k = threadIdx.x;
  int l = m >> 1;
  const float* W = (m & 1) ? (Wr + (size_t)l * HD * HD) : (Wl + (size_t)l * HD * HD);
  WT[((size_t)m * HD + n) * HD + k] = (_Float16)W[k * HD + n];
}

// ---------------- pre-transform: H16 = fp16(x @ pre_W + pre_b) ----------------
__global__ __launch_bounds__(256) void k_pre(const float* __restrict__ x,
    const float* __restrict__ W, const float* __restrict__ b,
    _Float16* __restrict__ H16)
{
  __shared__ float Ws[FI][HD];
  __shared__ float xs[8][FI];
  int r0 = blockIdx.x * 8;
  int t = threadIdx.x;
  for (int i = t; i < FI * HD; i += 256) Ws[i >> 8][i & 255] = W[i];
  if (t < 8 * FI) xs[t >> 4][t & 15] = x[(size_t)(r0 + (t >> 4)) * FI + (t & 15)];
  __syncthreads();
  float bj = b[t];
  for (int r = 0; r < 8; ++r) {
    float acc = bj;
#pragma unroll
    for (int k = 0; k < FI; ++k) acc += xs[r][k] * Ws[k][t];
    H16[(size_t)(r0 + r) * HD + t] = (_Float16)acc;
  }
}

// ---------------- CSR build ----------------
__global__ __launch_bounds__(256) void k_count(const int* __restrict__ ei, int* __restrict__ cnt)
{
  int i = blockIdx.x * 256 + threadIdx.x;
  if (i >= ETOT) return;
  int dst = (i < EE) ? ei[EE + i] : (i - EE);
  atomicAdd(&cnt[dst], 1);
}

__global__ __launch_bounds__(1024) void k_scan(const int* __restrict__ cnt,
    int* __restrict__ rowptr, int* __restrict__ wptr)
{
  __shared__ int wsum[16];
  __shared__ int carry;
  int t = threadIdx.x, wid = t >> 6, lane = t & 63;
  if (t == 0) carry = 0;
  __syncthreads();
  for (int base = 0; base < NN; base += 1024) {
    int i = base + t;
    int v0 = (i < NN) ? cnt[i] : 0;
    int v = v0;
#pragma unroll
    for (int d = 1; d < 64; d <<= 1) {
      int u = __shfl_up(v, d);
      if (lane >= d) v += u;
    }
    if (lane == 63) wsum[wid] = v;
    __syncthreads();
    int carry_cur = carry;
    if (t < 16) {
      int s = wsum[t];
#pragma unroll
      for (int d = 1; d < 16; d <<= 1) {
        int u = __shfl_up(s, d);
        if (t >= d) s += u;
      }
      wsum[t] = s;
    }
    __syncthreads();
    int woff = (wid > 0) ? wsum[wid - 1] : 0;
    int excl = carry_cur + woff + v - v0;
    if (i < NN) { rowptr[i] = excl; wptr[i] = excl; }
    __syncthreads();
    if (t == 0) carry = carry_cur + wsum[15];
    __syncthreads();
  }
  if (t == 0) rowptr[NN] = carry;
}

__global__ __launch_bounds__(256) void k_scatter(const int* __restrict__ ei,
    int* __restrict__ wptr, int* __restrict__ csr_src)
{
  int i = blockIdx.x * 256 + threadIdx.x;
  if (i >= ETOT) return;
  int src = (i < EE) ? ei[i] : (i - EE);
  int dst = (i < EE) ? ei[EE + i] : (i - EE);
  int pos = atomicAdd(&wptr[dst], 1);
  csr_src[pos] = src;
}

// ---------------- fp16 MFMA GEMM: Xl|Xr = H16 @ (WlT|WrT)^T ----------------
// grid = (MPAD/128, 4); block = 256 (4 waves, 2x2 of 64x64)
#define BK 64
__global__ __launch_bounds__(256) void k_gemm16(const _Float16* __restrict__ A,
    const _Float16* __restrict__ WT,   // this layer: [0]=WlT [1]=WrT, each [256][256]
    _Float16* __restrict__ Xl, _Float16* __restrict__ Xr)
{
  __shared__ __align__(16) _Float16 As[128 * BK];  // 16KB, rows of 64 elems, XOR-swizzled
  __shared__ __align__(16) _Float16 Bs[128 * BK];  // 16KB
  int t = threadIdx.x;
  int w = t >> 6, lane = t & 63;
  int row0 = blockIdx.x * 128;
  int ct = blockIdx.y;               // 0..3
  const _Float16* Bmat = WT + (size_t)(ct >> 1) * HD * HD + (size_t)(ct & 1) * 128 * HD;
  _Float16* Out = (ct >> 1) ? Xr : Xl;
  int j0 = (ct & 1) * 128;

  f32x4 acc[4][4] = {};
  int wr = w >> 1, wc = w & 1;

  for (int k0 = 0; k0 < HD; k0 += BK) {
#pragma unroll
    for (int i = 0; i < 4; ++i) {
      int p = (i * 4 + w) * 64 + lane;        // 16B-slot index 0..1023
      int row = p >> 3, s = p & 7;
      int g = s ^ (row & 7);                  // pre-swizzled global slot
      const _Float16* srcA = A + (size_t)(row0 + row) * HD + k0 + g * 8;
      __builtin_amdgcn_global_load_lds(
        (const __attribute__((address_space(1))) void*)srcA,
        (__attribute__((address_space(3))) void*)((char*)As + (i * 4 + w) * 1024),
        16, 0, 0);
      const _Float16* srcB = Bmat + (size_t)row * HD + k0 + g * 8;
      __builtin_amdgcn_global_load_lds(
        (const __attribute__((address_space(1))) void*)srcB,
        (__attribute__((address_space(3))) void*)((char*)Bs + (i * 4 + w) * 1024),
        16, 0, 0);
    }
    __syncthreads();
#pragma unroll
    for (int ks = 0; ks < 2; ++ks) {
      half8 af[4], bfr[4];
      int kslot = ks * 4 + (lane >> 4);
#pragma unroll
      for (int mi = 0; mi < 4; ++mi) {
        int rl = wr * 64 + mi * 16 + (lane & 15);
        int ps = kslot ^ (rl & 7);
        af[mi] = *(const half8*)((const char*)As + rl * 128 + ps * 16);
      }
#pragma unroll
      for (int ni = 0; ni < 4; ++ni) {
        int nl = wc * 64 + ni * 16 + (lane & 15);
        int ps = kslot ^ (nl & 7);
        bfr[ni] = *(const half8*)((const char*)Bs + nl * 128 + ps * 16);
      }
#pragma unroll
      for (int mi = 0; mi < 4; ++mi)
#pragma unroll
        for (int ni = 0; ni < 4; ++ni)
          acc[mi][ni] = __builtin_amdgcn_mfma_f32_16x16x32_f16(af[mi], bfr[ni], acc[mi][ni], 0, 0, 0);
    }
    __syncthreads();
  }
  int crow = (lane >> 4) * 4;
  int ccol = lane & 15;
#pragma unroll
  for (int mi = 0; mi < 4; ++mi)
#pragma unroll
    for (int ni = 0; ni < 4; ++ni) {
      size_t base_r = row0 + wr * 64 + mi * 16 + crow;
      int c = j0 + wc * 64 + ni * 16 + ccol;
#pragma unroll
      for (int r = 0; r < 4; ++r)
        Out[(base_r + r) * HD + c] = (_Float16)acc[mi][ni][r];
    }
}

// ---------------- fused edge logits + online-softmax aggregation ----------------
// one wave per node; block = 256 (4 nodes)
__global__ __launch_bounds__(256) void k_edgeagg(const _Float16* __restrict__ Xl,
    const _Float16* __restrict__ Xr, const float* __restrict__ attw,
    const float* __restrict__ bias, const int* __restrict__ rowptr,
    const int* __restrict__ csr_src, float* __restrict__ Hout,
    _Float16* __restrict__ H16)
{
  int node = blockIdx.x * 4 + (threadIdx.x >> 6);
  int lane = threadIdx.x & 63;
  if (node >= NN) return;
  int st = rowptr[node], en = rowptr[node + 1];
  int c = lane * 4;
  half4v xrv = *(const half4v*)(Xr + (size_t)node * HD + c);
  float r0 = (float)xrv[0], r1 = (float)xrv[1], r2 = (float)xrv[2], r3 = (float)xrv[3];
  float4 wv = *(const float4*)(attw + c);
  float mh = -1e30f, dsum = 0.f;
  float a0 = 0.f, a1 = 0.f, a2 = 0.f, a3 = 0.f;
  int src = csr_src[st];
  half4v xlv = *(const half4v*)(Xl + (size_t)src * HD + c);
  for (int i = st; i < en; ++i) {
    half4v xln = xlv;
    if (i + 1 < en) {
      int srcn = csr_src[i + 1];
      xln = *(const half4v*)(Xl + (size_t)srcn * HD + c);
    }
    float x0 = (float)xlv[0], x1 = (float)xlv[1], x2 = (float)xlv[2], x3 = (float)xlv[3];
    float m0 = x0 + r0; m0 = (m0 > 0.f) ? m0 : 0.2f * m0;
    float m1 = x1 + r1; m1 = (m1 > 0.f) ? m1 : 0.2f * m1;
    float m2 = x2 + r2; m2 = (m2 > 0.f) ? m2 : 0.2f * m2;
    float m3 = x3 + r3; m3 = (m3 > 0.f) ? m3 : 0.2f * m3;
    float e = wv.x * m0 + wv.y * m1 + wv.z * m2 + wv.w * m3;
    e += __shfl_xor(e, 1);
    e += __shfl_xor(e, 2);
    e += __shfl_xor(e, 4);   // all 8 lanes of head hold e
    float nm = fmaxf(mh, e);
    float sc = __expf(mh - nm);
    float pw = __expf(e - nm);
    a0 = a0 * sc + pw * x0;
    a1 = a1 * sc + pw * x1;
    a2 = a2 * sc + pw * x2;
    a3 = a3 * sc + pw * x3;
    dsum = dsum * sc + pw;
    mh = nm;
    xlv = xln;
  }
  float inv = 1.f / (dsum + 1e-16f);
  float4 bb = *(const float4*)(bias + c);
  float o0 = a0 * inv + bb.x, o1 = a1 * inv + bb.y;
  float o2 = a2 * inv + bb.z, o3 = a3 * inv + bb.w;
  o0 = (o0 > 0.f) ? o0 : expm1f(o0);
  o1 = (o1 > 0.f) ? o1 : expm1f(o1);
  o2 = (o2 > 0.f) ? o2 : expm1f(o2);
  o3 = (o3 > 0.f) ? o3 : expm1f(o3);
  *(float4*)(Hout + (size_t)node * HD + c) = make_float4(o0, o1, o2, o3);
  half4v h4;
  h4[0] = (_Float16)o0; h4[1] = (_Float16)o1; h4[2] = (_Float16)o2; h4[3] = (_Float16)o3;
  *(half4v*)(H16 + (size_t)node * HD + c) = h4;
}

// ---------------- global mean ----------------
__global__ __launch_bounds__(256) void k_gsum(const float* __restrict__ H,
    const int* __restrict__ batch, float* __restrict__ gsum, int* __restrict__ gcnt)
{
  int r0 = blockIdx.x * 128;
  int rend = r0 + 128; if (rend > NN) rend = NN;
  int c = threadIdx.x;
  float acc = 0.f; int cn = 0;
  for (int r = r0; r < rend; ++r) {
    if (batch[r] == 0) { acc += H[(size_t)r * HD + c]; cn++; }
  }
  atomicAdd(&gsum[c], acc);
  if (c == 0) atomicAdd(gcnt, cn);
}

__global__ __launch_bounds__(256) void k_gfin(const float* __restrict__ gsum,
    const int* __restrict__ gcnt, float* __restrict__ gvec)
{
  gvec[threadIdx.x] = gsum[threadIdx.x] / (float)(*gcnt);
}

// ---------------- sheet gather + mean ----------------
__global__ __launch_bounds__(256) void k_sheet(const float* __restrict__ H,
    const int* __restrict__ idx, float* __restrict__ sheet)
{
  int s = blockIdx.x, c = threadIdx.x;
  float acc = 0.f;
  for (int k = 0; k < KS; ++k) {
    int n = idx[s * KS + k];
    acc += H[(size_t)n * HD + c];
  }
  sheet[s * HD + c] = acc * (1.f / KS);
}

// ---------------- generic row-MLP: Y = act(LN(X @ W + b)) ----------------
template <int KD, int OD, bool LN, bool RELU>
__global__ __launch_bounds__(OD) void k_rowmlp(const float* __restrict__ X,
    const float* __restrict__ W, const float* __restrict__ B,
    const float* __restrict__ G, const float* __restrict__ Be,
    float* __restrict__ Y)
{
  __shared__ float xr[KD];
  __shared__ float red[OD];
  int row = blockIdx.x;
  for (int k = threadIdx.x; k < KD; k += OD) xr[k] = X[row * KD + k];
  __syncthreads();
  int j = threadIdx.x;
  float acc = B[j];
#pragma unroll 8
  for (int k = 0; k < KD; ++k) acc += xr[k] * W[k * OD + j];
  if (LN) {
    red[j] = acc; __syncthreads();
    for (int s = OD / 2; s > 0; s >>= 1) { if (j < s) red[j] += red[j + s]; __syncthreads(); }
    float mu = red[0] * (1.f / OD);
    __syncthreads();
    float d = acc - mu;
    red[j] = d * d; __syncthreads();
    for (int s = OD / 2; s > 0; s >>= 1) { if (j < s) red[j] += red[j + s]; __syncthreads(); }
    float var = red[0] * (1.f / OD);
    acc = d * rsqrtf(var + 1e-5f) * G[j] + Be[j];
  }
  if (RELU) acc = fmaxf(acc, 0.f);
  Y[row * OD + j] = acc;
}

// ---------------- cross-attention scores + softmax ----------------
__global__ __launch_bounds__(256) void k_caatt(const float* __restrict__ Q,
    const float* __restrict__ Km, float* __restrict__ att)
{
  int q = blockIdx.x, h = blockIdx.y;
  __shared__ float qv[HC];
  __shared__ float red[256];
  int t = threadIdx.x;
  if (t < HC) qv[t] = Q[q * HD + h * HC + t];
  __syncthreads();
  const float* kr = Km + t * HD + h * HC;
  float s = 0.f;
#pragma unroll 8
  for (int d = 0; d < HC; ++d) s += qv[d] * kr[d];
  s *= 0.125f;
  red[t] = s; __syncthreads();
  for (int st = 128; st > 0; st >>= 1) { if (t < st) red[t] = fmaxf(red[t], red[t + st]); __syncthreads(); }
  float mx = red[0]; __syncthreads();
  float ev = expf(s - mx);
  red[t] = ev; __syncthreads();
  for (int st = 128; st > 0; st >>= 1) { if (t < st) red[t] += red[t + st]; __syncthreads(); }
  att[((size_t)h * SS + q) * SS + t] = ev / red[0];
}

// ---------------- att @ V ----------------
__global__ __launch_bounds__(256) void k_capply(const float* __restrict__ att,
    const float* __restrict__ V, float* __restrict__ out)
{
  __shared__ float aw[NHC * SS];
  int q = blockIdx.x;
  for (int i = threadIdx.x; i < NHC * SS; i += 256) {
    int h = i >> 8, k = i & 255;
    aw[i] = att[((size_t)h * SS + q) * SS + k];
  }
  __syncthreads();
  int c = threadIdx.x, h = c >> 6;
  float acc = 0.f;
  for (int k = 0; k < SS; ++k) acc += aw[h * SS + k] * V[k * HD + c];
  out[q * HD + c] = acc;
}

// ---------------- concat [fused | g] ----------------
__global__ __launch_bounds__(256) void k_concat(const float* __restrict__ fused,
    const float* __restrict__ gvec, float* __restrict__ hqin)
{
  int s = blockIdx.x, t = threadIdx.x;
  hqin[s * 512 + t] = fused[s * HD + t];
  hqin[s * 512 + 256 + t] = gvec[t];
}

// ---------------- q_values ----------------
__global__ __launch_bounds__(128) void k_qval(const float* __restrict__ hq2,
    const float* __restrict__ W3, const float* __restrict__ b3, float* __restrict__ out)
{
  int s = blockIdx.x, j = threadIdx.x;
  __shared__ float red[128];
  red[j] = hq2[s * 128 + j] * W3[j];
  __syncthreads();
  for (int st = 64; st > 0; st >>= 1) { if (j < st) red[j] += red[j + st]; __syncthreads(); }
  if (j == 0) out[s] = red[0] + b3[0];
}

// ---------------- done predictor ----------------
__global__ __launch_bounds__(128) void k_done(const float* __restrict__ gvec,
    const float* __restrict__ W1, const float* __restrict__ b1,
    const float* __restrict__ g1, const float* __restrict__ be1,
    const float* __restrict__ W2, const float* __restrict__ b2,
    float* __restrict__ out)
{
  __shared__ float gl[256];
  __shared__ float red[128];
  int j = threadIdx.x;
  gl[j] = gvec[j]; gl[j + 128] = gvec[j + 128];
  __syncthreads();
  float acc = b1[j];
  for (int k = 0; k < 256; ++k) acc += gl[k] * W1[k * 128 + j];
  red[j] = acc; __syncthreads();
  for (int st = 64; st > 0; st >>= 1) { if (j < st) red[j] += red[j + st]; __syncthreads(); }
  float mu = red[0] * (1.f / 128.f); __syncthreads();
  float d = acc - mu;
  red[j] = d * d; __syncthreads();
  for (int st = 64; st > 0; st >>= 1) { if (j < st) red[j] += red[j + st]; __syncthreads(); }
  float var = red[0] * (1.f / 128.f);
  float hd = fmaxf(d * rsqrtf(var + 1e-5f) * g1[j] + be1[j], 0.f);
  __syncthreads();
  red[j] = hd * W2[j]; __syncthreads();
  for (int st = 64; st > 0; st >>= 1) { if (j < st) red[j] += red[j + st]; __syncthreads(); }
  if (j == 0) out[0] = red[0] + b2[0];
}

// =====================================================================
extern "C" void kernel_launch(void* const* d_in, const int* in_sizes, int n_in,
                              void* d_out, int out_size, void* d_ws, size_t ws_size,
                              hipStream_t stream) {
  const float* x      = (const float*)d_in[0];
  const int*   ei     = (const int*)d_in[1];
  const int*   batch  = (const int*)d_in[2];
  const int*   sheet_idx = (const int*)d_in[3];
  const float* sheet_feat = (const float*)d_in[4];
  const float* pre_W  = (const float*)d_in[5];
  const float* pre_b  = (const float*)d_in[6];
  const float* gat_Wl = (const float*)d_in[7];
  const float* gat_Wr = (const float*)d_in[8];
  const float* gat_att = (const float*)d_in[9];
  const float* gat_b  = (const float*)d_in[10];
  const float* geo_W1 = (const float*)d_in[11];
  const float* geo_b1 = (const float*)d_in[12];
  const float* geo_g1 = (const float*)d_in[13];
  const float* geo_be1 = (const float*)d_in[14];
  const float* geo_W2 = (const float*)d_in[15];
  const float* geo_b2 = (const float*)d_in[16];
  const float* geo_g2 = (const float*)d_in[17];
  const float* geo_be2 = (const float*)d_in[18];
  const float* ca_Wq = (const float*)d_in[19];
  const float* ca_bq = (const float*)d_in[20];
  const float* ca_Wk = (const float*)d_in[21];
  const float* ca_bk = (const float*)d_in[22];
  const float* ca_Wv = (const float*)d_in[23];
  const float* ca_bv = (const float*)d_in[24];
  const float* ca_Wo = (const float*)d_in[25];
  const float* ca_bo = (const float*)d_in[26];
  const float* q_W1 = (const float*)d_in[27];
  const float* q_b1 = (const float*)d_in[28];
  const float* q_g1 = (const float*)d_in[29];
  const float* q_be1 = (const float*)d_in[30];
  const float* q_W2 = (const float*)d_in[31];
  const float* q_b2 = (const float*)d_in[32];
  const float* q_g2 = (const float*)d_in[33];
  const float* q_be2 = (const float*)d_in[34];
  const float* q_W3 = (const float*)d_in[35];
  const float* q_b3 = (const float*)d_in[36];
  const float* d_W1 = (const float*)d_in[37];
  const float* d_b1 = (const float*)d_in[38];
  const float* d_g1 = (const float*)d_in[39];
  const float* d_be1 = (const float*)d_in[40];
  const float* d_W2 = (const float*)d_in[41];
  const float* d_b2 = (const float*)d_in[42];

  char* wsb = (char*)d_ws;
  auto alloc = [&](size_t bytes) { char* p = wsb; wsb += (bytes + 255) & ~(size_t)255; return p; };

  _Float16* h16  = (_Float16*)alloc((size_t)MPAD * HD * 2);
  _Float16* Xl16 = (_Float16*)alloc((size_t)MPAD * HD * 2);
  _Float16* Xr16 = (_Float16*)alloc((size_t)MPAD * HD * 2);
  _Float16* WT   = (_Float16*)alloc((size_t)6 * HD * HD * 2);
  float* bufA    = (float*)alloc((size_t)NN * HD * 4);
  float* gsum    = (float*)alloc(256 * 4);
  float* gvec    = (float*)alloc(256 * 4);
  float* sheetb  = (float*)alloc(SS * HD * 4);
  float* geo1b   = (float*)alloc(SS * HD * 4);
  float* geo2b   = (float*)alloc(SS * HD * 4);
  float* qb      = (float*)alloc(SS * HD * 4);
  float* kb      = (float*)alloc(SS * HD * 4);
  float* vb      = (float*)alloc(SS * HD * 4);
  float* attb    = (float*)alloc((size_t)NHC * SS * SS * 4);
  float* pvb     = (float*)alloc(SS * HD * 4);
  float* fusedb  = (float*)alloc(SS * HD * 4);
  float* hqin    = (float*)alloc(SS * 512 * 4);
  float* hq1b    = (float*)alloc(SS * HD * 4);
  float* hq2b    = (float*)alloc(SS * 128 * 4);
  int* cnt       = (int*)alloc((size_t)NN * 4);
  int* rowptr    = (int*)alloc((size_t)(NN + 1) * 4);
  int* wptr      = (int*)alloc((size_t)NN * 4);
  int* csr_src   = (int*)alloc((size_t)ETOT * 4);
  int* gcnt      = (int*)alloc(4);

  float* out_q = (float*)d_out;        // [256]
  float* out_d = out_q + SS;           // [1]

  hipMemsetAsync(cnt, 0, (size_t)NN * sizeof(int), stream);
  hipMemsetAsync(gsum, 0, 256 * sizeof(float), stream);
  hipMemsetAsync(gcnt, 0, sizeof(int), stream);
  hipMemsetAsync(h16 + (size_t)NN * HD, 0, (size_t)(MPAD - NN) * HD * 2, stream);

  // CSR build
  k_count<<<(ETOT + 255) / 256, 256, 0, stream>>>(ei, cnt);
  k_scan<<<1, 1024, 0, stream>>>(cnt, rowptr, wptr);
  k_scatter<<<(ETOT + 255) / 256, 256, 0, stream>>>(ei, wptr, csr_src);

  // weights + pre-transform
  k_wconv<<<6 * 256, 256, 0, stream>>>(gat_Wl, gat_Wr, WT);
  k_pre<<<NN / 8, 256, 0, stream>>>(x, pre_W, pre_b, h16);

  // GAT layers
  dim3 ggrid(MPAD / 128, 4);
  for (int l = 0; l < NL; ++l) {
    k_gemm16<<<ggrid, 256, 0, stream>>>(h16, WT + (size_t)l * 2 * HD * HD, Xl16, Xr16);
    k_edgeagg<<<(NN + 3) / 4, 256, 0, stream>>>(Xl16, Xr16, gat_att + l * NH * CH,
                                                gat_b + l * HD, rowptr, csr_src, bufA, h16);
  }

  // global mean
  k_gsum<<<(NN + 127) / 128, 256, 0, stream>>>(bufA, batch, gsum, gcnt);
  k_gfin<<<1, 256, 0, stream>>>(gsum, gcnt, gvec);

  // sheet pooling
  k_sheet<<<SS, 256, 0, stream>>>(bufA, sheet_idx, sheetb);

  // geometry encoder
  k_rowmlp<16, 256, true, true><<<SS, 256, 0, stream>>>(sheet_feat, geo_W1, geo_b1, geo_g1, geo_be1, geo1b);
  k_rowmlp<256, 256, true, true><<<SS, 256, 0, stream>>>(geo1b, geo_W2, geo_b2, geo_g2, geo_be2, geo2b);

  // cross attention
  k_rowmlp<256, 256, false, false><<<SS, 256, 0, stream>>>(sheetb, ca_Wq, ca_bq, nullptr, nullptr, qb);
  k_rowmlp<256, 256, false, false><<<SS, 256, 0, stream>>>(geo2b, ca_Wk, ca_bk, nullptr, nullptr, kb);
  k_rowmlp<256, 256, false, false><<<SS, 256, 0, stream>>>(geo2b, ca_Wv, ca_bv, nullptr, nullptr, vb);
  dim3 agrid(SS, NHC);
  k_caatt<<<agrid, 256, 0, stream>>>(qb, kb, attb);
  k_capply<<<SS, 256, 0, stream>>>(attb, vb, pvb);
  k_rowmlp<256, 256, false, false><<<SS, 256, 0, stream>>>(pvb, ca_Wo, ca_bo, nullptr, nullptr, fusedb);

  // q-MLP
  k_concat<<<SS, 256, 0, stream>>>(fusedb, gvec, hqin);
  k_rowmlp<512, 256, true, true><<<SS, 256, 0, stream>>>(hqin, q_W1, q_b1, q_g1, q_be1, hq1b);
  k_rowmlp<256, 128, true, true><<<SS, 128, 0, stream>>>(hq1b, q_W2, q_b2, q_g2, q_be2, hq2b);
  k_qval<<<SS, 128, 0, stream>>>(hq2b, q_W3, q_b3, out_q);

  // done predictor
  k_done<<<1, 128, 0, stream>>>(gvec, d_W1, d_b1, d_g1, d_be1, d_W2, d_b2, out_d);
}

// Round 3
// 474.577 us; speedup vs baseline: 2.3365x; 1.0460x over previous
//
#include <hip/hip_runtime.h>
#include <hip/hip_bf16.h>
#include <stdint.h>

#define NN 30000
#define MPAD 30080
#define FI 16
#define EE 300000
#define ETOT (EE + NN)
#define HD 256
#define NH 8
#define CH 32
#define NL 3
#define SS 256
#define KS 128
#define NHC 4
#define HC 64

typedef _Float16 half8 __attribute__((ext_vector_type(8)));
typedef _Float16 half4v __attribute__((ext_vector_type(4)));
typedef float f32x4 __attribute__((ext_vector_type(4)));

// ---------------- weight transpose+convert: WT[m][n][k] = W_m[k][n] ----------------
__global__ __launch_bounds__(256) void k_wconv(const float* __restrict__ Wl,
    const float* __restrict__ Wr, _Float16* __restrict__ WT)
{
  int m = blockIdx.x >> 8;       // 0..5 : l*2 + (0=Wl,1=Wr)
  int n = blockIdx.x & 255;
  int k = threadIdx.x;
  int l = m >> 1;
  const float* W = (m & 1) ? (Wr + (size_t)l * HD * HD) : (Wl + (size_t)l * HD * HD);
  WT[((size_t)m * HD + n) * HD + k] = (_Float16)W[k * HD + n];
}

// ---------------- pre-transform: H16 = fp16(x @ pre_W + pre_b) ----------------
__global__ __launch_bounds__(256) void k_pre(const float* __restrict__ x,
    const float* __restrict__ W, const float* __restrict__ b,
    _Float16* __restrict__ H16)
{
  __shared__ float Ws[FI][HD];
  __shared__ float xs[8][FI];
  int r0 = blockIdx.x * 8;
  int t = threadIdx.x;
  for (int i = t; i < FI * HD; i += 256) Ws[i >> 8][i & 255] = W[i];
  if (t < 8 * FI) xs[t >> 4][t & 15] = x[(size_t)(r0 + (t >> 4)) * FI + (t & 15)];
  __syncthreads();
  float bj = b[t];
  for (int r = 0; r < 8; ++r) {
    float acc = bj;
#pragma unroll
    for (int k = 0; k < FI; ++k) acc += xs[r][k] * Ws[k][t];
    H16[(size_t)(r0 + r) * HD + t] = (_Float16)acc;
  }
}

// ---------------- CSR build ----------------
__global__ __launch_bounds__(256) void k_count(const int* __restrict__ ei, int* __restrict__ cnt)
{
  int i = blockIdx.x * 256 + threadIdx.x;
  if (i >= ETOT) return;
  int dst = (i < EE) ? ei[EE + i] : (i - EE);
  atomicAdd(&cnt[dst], 1);
}

__global__ __launch_bounds__(1024) void k_scan(const int* __restrict__ cnt,
    int* __restrict__ rowptr, int* __restrict__ wptr)
{
  __shared__ int wsum[16];
  __shared__ int carry;
  int t = threadIdx.x, wid = t >> 6, lane = t & 63;
  if (t == 0) carry = 0;
  __syncthreads();
  for (int base = 0; base < NN; base += 1024) {
    int i = base + t;
    int v0 = (i < NN) ? cnt[i] : 0;
    int v = v0;
#pragma unroll
    for (int d = 1; d < 64; d <<= 1) {
      int u = __shfl_up(v, d);
      if (lane >= d) v += u;
    }
    if (lane == 63) wsum[wid] = v;
    __syncthreads();
    int carry_cur = carry;
    if (t < 16) {
      int s = wsum[t];
#pragma unroll
      for (int d = 1; d < 16; d <<= 1) {
        int u = __shfl_up(s, d);
        if (t >= d) s += u;
      }
      wsum[t] = s;
    }
    __syncthreads();
    int woff = (wid > 0) ? wsum[wid - 1] : 0;
    int excl = carry_cur + woff + v - v0;
    if (i < NN) { rowptr[i] = excl; wptr[i] = excl; }
    __syncthreads();
    if (t == 0) carry = carry_cur + wsum[15];
    __syncthreads();
  }
  if (t == 0) rowptr[NN] = carry;
}

__global__ __launch_bounds__(256) void k_scatter(const int* __restrict__ ei,
    int* __restrict__ wptr, int* __restrict__ csr_src)
{
  int i = blockIdx.x * 256 + threadIdx.x;
  if (i >= ETOT) return;
  int src = (i < EE) ? ei[i] : (i - EE);
  int dst = (i < EE) ? ei[EE + i] : (i - EE);
  int pos = atomicAdd(&wptr[dst], 1);
  csr_src[pos] = src;
}

// ---------------- fp16 MFMA GEMM: Xl|Xr = H16 @ (WlT|WrT)^T ----------------
#define BK 64
__global__ __launch_bounds__(256) void k_gemm16(const _Float16* __restrict__ A,
    const _Float16* __restrict__ WT,
    _Float16* __restrict__ Xl, _Float16* __restrict__ Xr)
{
  __shared__ __align__(16) _Float16 As[128 * BK];
  __shared__ __align__(16) _Float16 Bs[128 * BK];
  int t = threadIdx.x;
  int w = t >> 6, lane = t & 63;
  int row0 = blockIdx.x * 128;
  int ct = blockIdx.y;               // 0..3
  const _Float16* Bmat = WT + (size_t)(ct >> 1) * HD * HD + (size_t)(ct & 1) * 128 * HD;
  _Float16* Out = (ct >> 1) ? Xr : Xl;
  int j0 = (ct & 1) * 128;

  f32x4 acc[4][4] = {};
  int wr = w >> 1, wc = w & 1;

  for (int k0 = 0; k0 < HD; k0 += BK) {
#pragma unroll
    for (int i = 0; i < 4; ++i) {
      int p = (i * 4 + w) * 64 + lane;
      int row = p >> 3, s = p & 7;
      int g = s ^ (row & 7);
      const _Float16* srcA = A + (size_t)(row0 + row) * HD + k0 + g * 8;
      __builtin_amdgcn_global_load_lds(
        (const __attribute__((address_space(1))) void*)srcA,
        (__attribute__((address_space(3))) void*)((char*)As + (i * 4 + w) * 1024),
        16, 0, 0);
      const _Float16* srcB = Bmat + (size_t)row * HD + k0 + g * 8;
      __builtin_amdgcn_global_load_lds(
        (const __attribute__((address_space(1))) void*)srcB,
        (__attribute__((address_space(3))) void*)((char*)Bs + (i * 4 + w) * 1024),
        16, 0, 0);
    }
    __syncthreads();
#pragma unroll
    for (int ks = 0; ks < 2; ++ks) {
      half8 af[4], bfr[4];
      int kslot = ks * 4 + (lane >> 4);
#pragma unroll
      for (int mi = 0; mi < 4; ++mi) {
        int rl = wr * 64 + mi * 16 + (lane & 15);
        int ps = kslot ^ (rl & 7);
        af[mi] = *(const half8*)((const char*)As + rl * 128 + ps * 16);
      }
#pragma unroll
      for (int ni = 0; ni < 4; ++ni) {
        int nl = wc * 64 + ni * 16 + (lane & 15);
        int ps = kslot ^ (nl & 7);
        bfr[ni] = *(const half8*)((const char*)Bs + nl * 128 + ps * 16);
      }
#pragma unroll
      for (int mi = 0; mi < 4; ++mi)
#pragma unroll
        for (int ni = 0; ni < 4; ++ni)
          acc[mi][ni] = __builtin_amdgcn_mfma_f32_16x16x32_f16(af[mi], bfr[ni], acc[mi][ni], 0, 0, 0);
    }
    __syncthreads();
  }
  int crow = (lane >> 4) * 4;
  int ccol = lane & 15;
#pragma unroll
  for (int mi = 0; mi < 4; ++mi)
#pragma unroll
    for (int ni = 0; ni < 4; ++ni) {
      size_t base_r = row0 + wr * 64 + mi * 16 + crow;
      int c = j0 + wc * 64 + ni * 16 + ccol;
#pragma unroll
      for (int r = 0; r < 4; ++r)
        Out[(base_r + r) * HD + c] = (_Float16)acc[mi][ni][r];
    }
}

// ---------------- fused edge logits + online-softmax aggregation ----------------
// one wave per node; 2-edge unrolled pipeline; writes fp16 H only
__global__ __launch_bounds__(256) void k_edgeagg(const _Float16* __restrict__ Xl,
    const _Float16* __restrict__ Xr, const float* __restrict__ attw,
    const float* __restrict__ bias, const int* __restrict__ rowptr,
    const int* __restrict__ csr_src, _Float16* __restrict__ H16)
{
  int node = blockIdx.x * 4 + (threadIdx.x >> 6);
  int lane = threadIdx.x & 63;
  if (node >= NN) return;
  int st = rowptr[node], en = rowptr[node + 1];
  int c = lane * 4;
  half4v xrv = *(const half4v*)(Xr + (size_t)node * HD + c);
  float r0 = (float)xrv[0], r1 = (float)xrv[1], r2 = (float)xrv[2], r3 = (float)xrv[3];
  float4 wv = *(const float4*)(attw + c);
  float mh = -1e30f, dsum = 0.f;
  float a0 = 0.f, a1 = 0.f, a2 = 0.f, a3 = 0.f;

  half4v v0 = *(const half4v*)(Xl + (size_t)csr_src[st] * HD + c);
  half4v v1 = {};
  if (st + 1 < en) v1 = *(const half4v*)(Xl + (size_t)csr_src[st + 1] * HD + c);

  for (int i = st; i < en; i += 2) {
    bool has1 = (i + 1 < en);
    half4v p0 = {}, p1 = {};
    if (i + 2 < en) p0 = *(const half4v*)(Xl + (size_t)csr_src[i + 2] * HD + c);
    if (i + 3 < en) p1 = *(const half4v*)(Xl + (size_t)csr_src[i + 3] * HD + c);

    float x00 = (float)v0[0], x01 = (float)v0[1], x02 = (float)v0[2], x03 = (float)v0[3];
    float x10 = (float)v1[0], x11 = (float)v1[1], x12 = (float)v1[2], x13 = (float)v1[3];

    float m, e0 = 0.f, e1 = 0.f;
    m = x00 + r0; m = (m > 0.f) ? m : 0.2f * m; e0 += wv.x * m;
    m = x01 + r1; m = (m > 0.f) ? m : 0.2f * m; e0 += wv.y * m;
    m = x02 + r2; m = (m > 0.f) ? m : 0.2f * m; e0 += wv.z * m;
    m = x03 + r3; m = (m > 0.f) ? m : 0.2f * m; e0 += wv.w * m;
    m = x10 + r0; m = (m > 0.f) ? m : 0.2f * m; e1 += wv.x * m;
    m = x11 + r1; m = (m > 0.f) ? m : 0.2f * m; e1 += wv.y * m;
    m = x12 + r2; m = (m > 0.f) ? m : 0.2f * m; e1 += wv.z * m;
    m = x13 + r3; m = (m > 0.f) ? m : 0.2f * m; e1 += wv.w * m;
    e0 += __shfl_xor(e0, 1); e1 += __shfl_xor(e1, 1);
    e0 += __shfl_xor(e0, 2); e1 += __shfl_xor(e1, 2);
    e0 += __shfl_xor(e0, 4); e1 += __shfl_xor(e1, 4);
    if (!has1) e1 = -1e30f;

    float nm = fmaxf(mh, fmaxf(e0, e1));
    float sc = __expf(mh - nm);
    float pw0 = __expf(e0 - nm);
    float pw1 = __expf(e1 - nm);
    a0 = a0 * sc + pw0 * x00 + pw1 * x10;
    a1 = a1 * sc + pw0 * x01 + pw1 * x11;
    a2 = a2 * sc + pw0 * x02 + pw1 * x12;
    a3 = a3 * sc + pw0 * x03 + pw1 * x13;
    dsum = dsum * sc + pw0 + pw1;
    mh = nm;
    v0 = p0; v1 = p1;
  }
  float inv = 1.f / (dsum + 1e-16f);
  float4 bb = *(const float4*)(bias + c);
  float o0 = a0 * inv + bb.x, o1 = a1 * inv + bb.y;
  float o2 = a2 * inv + bb.z, o3 = a3 * inv + bb.w;
  o0 = (o0 > 0.f) ? o0 : expm1f(o0);
  o1 = (o1 > 0.f) ? o1 : expm1f(o1);
  o2 = (o2 > 0.f) ? o2 : expm1f(o2);
  o3 = (o3 > 0.f) ? o3 : expm1f(o3);
  half4v h4;
  h4[0] = (_Float16)o0; h4[1] = (_Float16)o1; h4[2] = (_Float16)o2; h4[3] = (_Float16)o3;
  *(half4v*)(H16 + (size_t)node * HD + c) = h4;
}

// ---------------- global sum over nodes (fp16 input) ----------------
__global__ __launch_bounds__(256) void k_gsum(const _Float16* __restrict__ H,
    const int* __restrict__ batch, float* __restrict__ gsum, int* __restrict__ gcnt)
{
  int r0 = blockIdx.x * 256;
  int rend = r0 + 256; if (rend > NN) rend = NN;
  int lane = threadIdx.x & 63, grp = threadIdx.x >> 6;
  int c = lane * 4;
  float a0 = 0.f, a1 = 0.f, a2 = 0.f, a3 = 0.f; int cn = 0;
  for (int r = r0 + grp; r < rend; r += 4) {
    if (batch[r] == 0) {
      half4v v = *(const half4v*)(H + (size_t)r * HD + c);
      a0 += (float)v[0]; a1 += (float)v[1]; a2 += (float)v[2]; a3 += (float)v[3];
      cn++;
    }
  }
  atomicAdd(&gsum[c + 0], a0);
  atomicAdd(&gsum[c + 1], a1);
  atomicAdd(&gsum[c + 2], a2);
  atomicAdd(&gsum[c + 3], a3);
  if (lane == 0) atomicAdd(gcnt, cn);
}

// ---------------- block LayerNorm helper (256 threads, n active) ----------------
__device__ __forceinline__ float ln_relu256(float a, int j, float* red,
    const float* __restrict__ G, const float* __restrict__ Be, int n, bool relu)
{
  bool active = j < n;
  red[j] = active ? a : 0.f;
  __syncthreads();
  for (int s = 128; s > 0; s >>= 1) { if (j < s) red[j] += red[j + s]; __syncthreads(); }
  float mu = red[0] / n;
  __syncthreads();
  float d = a - mu;
  red[j] = active ? d * d : 0.f;
  __syncthreads();
  for (int s = 128; s > 0; s >>= 1) { if (j < s) red[j] += red[j + s]; __syncthreads(); }
  float var = red[0] / n;
  __syncthreads();
  float o = 0.f;
  if (active) {
    o = d * rsqrtf(var + 1e-5f) * G[j] + Be[j];
    if (relu) o = fmaxf(o, 0.f);
  }
  return o;
}

// ---------------- tail1: sheet pool + geo encoder + Q/K/V ----------------
__global__ __launch_bounds__(256) void k_tail1(const _Float16* __restrict__ h16,
    const int* __restrict__ sheet_idx, const float* __restrict__ sheet_feat,
    const float* __restrict__ geo_W1, const float* __restrict__ geo_b1,
    const float* __restrict__ geo_g1, const float* __restrict__ geo_be1,
    const float* __restrict__ geo_W2, const float* __restrict__ geo_b2,
    const float* __restrict__ geo_g2, const float* __restrict__ geo_be2,
    const float* __restrict__ ca_Wq, const float* __restrict__ ca_bq,
    const float* __restrict__ ca_Wk, const float* __restrict__ ca_bk,
    const float* __restrict__ ca_Wv, const float* __restrict__ ca_bv,
    float* __restrict__ qb, float* __restrict__ kb, float* __restrict__ vb)
{
  __shared__ float sh[HD];
  __shared__ float g1v[HD];
  __shared__ float g2v[HD];
  __shared__ float red[256];
  __shared__ float xf[FI];
  int s = blockIdx.x, j = threadIdx.x;

  float acc = 0.f;
  for (int k = 0; k < KS; ++k) {
    int n = sheet_idx[s * KS + k];
    acc += (float)h16[(size_t)n * HD + j];
  }
  sh[j] = acc * (1.f / KS);
  if (j < FI) xf[j] = sheet_feat[s * FI + j];
  __syncthreads();

  // geo1 = relu(LN(xf @ W1 + b1))
  float a = geo_b1[j];
#pragma unroll
  for (int k = 0; k < FI; ++k) a += xf[k] * geo_W1[k * HD + j];
  g1v[j] = ln_relu256(a, j, red, geo_g1, geo_be1, HD, true);
  __syncthreads();

  // geo2 = relu(LN(g1 @ W2 + b2))
  a = geo_b2[j];
#pragma unroll 8
  for (int k = 0; k < HD; ++k) a += g1v[k] * geo_W2[k * HD + j];
  g2v[j] = ln_relu256(a, j, red, geo_g2, geo_be2, HD, true);
  __syncthreads();

  // q from sheet, k/v from geo2
  float aq = ca_bq[j], ak = ca_bk[j], av = ca_bv[j];
#pragma unroll 8
  for (int k = 0; k < HD; ++k) {
    float shk = sh[k], g2k = g2v[k];
    aq += shk * ca_Wq[k * HD + j];
    ak += g2k * ca_Wk[k * HD + j];
    av += g2k * ca_Wv[k * HD + j];
  }
  qb[s * HD + j] = aq;
  kb[s * HD + j] = ak;
  vb[s * HD + j] = av;
}

// ---------------- tail2: cross-attention + q-MLP ----------------
__global__ __launch_bounds__(256) void k_tail2(const float* __restrict__ qb,
    const float* __restrict__ kb, const float* __restrict__ vb,
    const float* __restrict__ ca_Wo, const float* __restrict__ ca_bo,
    const float* __restrict__ gsum, const int* __restrict__ gcnt,
    const float* __restrict__ q_W1, const float* __restrict__ q_b1,
    const float* __restrict__ q_g1, const float* __restrict__ q_be1,
    const float* __restrict__ q_W2, const float* __restrict__ q_b2,
    const float* __restrict__ q_g2, const float* __restrict__ q_be2,
    const float* __restrict__ q_W3, const float* __restrict__ q_b3,
    float* __restrict__ out_q)
{
  __shared__ float qv[HD];
  __shared__ float att[NHC][SS];
  __shared__ float pv[HD];
  __shared__ float fu[HD];
  __shared__ float gv[HD];
  __shared__ float hq1[HD];
  __shared__ float hq2[128];
  __shared__ float red[256];
  int q = blockIdx.x, t = threadIdx.x;

  qv[t] = qb[q * HD + t];
  gv[t] = gsum[t] / (float)(*gcnt);
  __syncthreads();

  // scores: thread t = key index
#pragma unroll
  for (int h = 0; h < NHC; ++h) {
    const float* kr = kb + (size_t)t * HD + h * HC;
    const float* qh = qv + h * HC;
    float sc = 0.f;
#pragma unroll 8
    for (int d = 0; d < HC; ++d) sc += qh[d] * kr[d];
    att[h][t] = sc * 0.125f;
  }
  __syncthreads();

  // softmax per head over keys
#pragma unroll
  for (int h = 0; h < NHC; ++h) {
    float v = att[h][t];
    red[t] = v; __syncthreads();
    for (int s = 128; s > 0; s >>= 1) { if (t < s) red[t] = fmaxf(red[t], red[t + s]); __syncthreads(); }
    float mx = red[0]; __syncthreads();
    float ev = __expf(v - mx);
    red[t] = ev; __syncthreads();
    for (int s = 128; s > 0; s >>= 1) { if (t < s) red[t] += red[t + s]; __syncthreads(); }
    att[h][t] = ev / red[0];
    __syncthreads();
  }

  // pv
  {
    int h = t >> 6;
    float acc = 0.f;
    for (int k = 0; k < SS; ++k) acc += att[h][k] * vb[(size_t)k * HD + t];
    pv[t] = acc;
  }
  __syncthreads();

  // fused = pv @ Wo + bo
  {
    float f = ca_bo[t];
#pragma unroll 8
    for (int k = 0; k < HD; ++k) f += pv[k] * ca_Wo[k * HD + t];
    fu[t] = f;
  }
  __syncthreads();

  // hq1 = relu(LN([fu|gv] @ qW1 + b1))
  float a = q_b1[t];
#pragma unroll 8
  for (int k = 0; k < HD; ++k) a += fu[k] * q_W1[k * HD + t];
#pragma unroll 8
  for (int k = 0; k < HD; ++k) a += gv[k] * q_W1[(HD + k) * HD + t];
  hq1[t] = ln_relu256(a, t, red, q_g1, q_be1, HD, true);
  __syncthreads();

  // hq2 = relu(LN(hq1 @ qW2 + b2)), 128-dim
  float a2 = 0.f;
  if (t < 128) {
    a2 = q_b2[t];
#pragma unroll 8
    for (int k = 0; k < HD; ++k) a2 += hq1[k] * q_W2[k * 128 + t];
  }
  float h2 = ln_relu256(a2, t, red, q_g2, q_be2, 128, true);
  if (t < 128) hq2[t] = h2;
  __syncthreads();

  // out = hq2 @ W3 + b3
  red[t] = (t < 128) ? hq2[t] * q_W3[t] : 0.f;
  __syncthreads();
  for (int s = 128; s > 0; s >>= 1) { if (t < s) red[t] += red[t + s]; __syncthreads(); }
  if (t == 0) out_q[q] = red[0] + q_b3[0];
}

// ---------------- done predictor ----------------
__global__ __launch_bounds__(128) void k_done(const float* __restrict__ gsum,
    const int* __restrict__ gcnt,
    const float* __restrict__ W1, const float* __restrict__ b1,
    const float* __restrict__ g1, const float* __restrict__ be1,
    const float* __restrict__ W2, const float* __restrict__ b2,
    float* __restrict__ out)
{
  __shared__ float gl[256];
  __shared__ float red[128];
  int j = threadIdx.x;
  float icnt = 1.f / (float)(*gcnt);
  gl[j] = gsum[j] * icnt; gl[j + 128] = gsum[j + 128] * icnt;
  __syncthreads();
  float acc = b1[j];
  for (int k = 0; k < 256; ++k) acc += gl[k] * W1[k * 128 + j];
  red[j] = acc; __syncthreads();
  for (int st = 64; st > 0; st >>= 1) { if (j < st) red[j] += red[j + st]; __syncthreads(); }
  float mu = red[0] * (1.f / 128.f); __syncthreads();
  float d = acc - mu;
  red[j] = d * d; __syncthreads();
  for (int st = 64; st > 0; st >>= 1) { if (j < st) red[j] += red[j + st]; __syncthreads(); }
  float var = red[0] * (1.f / 128.f);
  float hd = fmaxf(d * rsqrtf(var + 1e-5f) * g1[j] + be1[j], 0.f);
  __syncthreads();
  red[j] = hd * W2[j]; __syncthreads();
  for (int st = 64; st > 0; st >>= 1) { if (j < st) red[j] += red[j + st]; __syncthreads(); }
  if (j == 0) out[0] = red[0] + b2[0];
}

// =====================================================================
extern "C" void kernel_launch(void* const* d_in, const int* in_sizes, int n_in,
                              void* d_out, int out_size, void* d_ws, size_t ws_size,
                              hipStream_t stream) {
  const float* x      = (const float*)d_in[0];
  const int*   ei     = (const int*)d_in[1];
  const int*   batch  = (const int*)d_in[2];
  const int*   sheet_idx = (const int*)d_in[3];
  const float* sheet_feat = (const float*)d_in[4];
  const float* pre_W  = (const float*)d_in[5];
  const float* pre_b  = (const float*)d_in[6];
  const float* gat_Wl = (const float*)d_in[7];
  const float* gat_Wr = (const float*)d_in[8];
  const float* gat_att = (const float*)d_in[9];
  const float* gat_b  = (const float*)d_in[10];
  const float* geo_W1 = (const float*)d_in[11];
  const float* geo_b1 = (const float*)d_in[12];
  const float* geo_g1 = (const float*)d_in[13];
  const float* geo_be1 = (const float*)d_in[14];
  const float* geo_W2 = (const float*)d_in[15];
  const float* geo_b2 = (const float*)d_in[16];
  const float* geo_g2 = (const float*)d_in[17];
  const float* geo_be2 = (const float*)d_in[18];
  const float* ca_Wq = (const float*)d_in[19];
  const float* ca_bq = (const float*)d_in[20];
  const float* ca_Wk = (const float*)d_in[21];
  const float* ca_bk = (const float*)d_in[22];
  const float* ca_Wv = (const float*)d_in[23];
  const float* ca_bv = (const float*)d_in[24];
  const float* ca_Wo = (const float*)d_in[25];
  const float* ca_bo = (const float*)d_in[26];
  const float* q_W1 = (const float*)d_in[27];
  const float* q_b1 = (const float*)d_in[28];
  const float* q_g1 = (const float*)d_in[29];
  const float* q_be1 = (const float*)d_in[30];
  const float* q_W2 = (const float*)d_in[31];
  const float* q_b2 = (const float*)d_in[32];
  const float* q_g2 = (const float*)d_in[33];
  const float* q_be2 = (const float*)d_in[34];
  const float* q_W3 = (const float*)d_in[35];
  const float* q_b3 = (const float*)d_in[36];
  const float* d_W1 = (const float*)d_in[37];
  const float* d_b1 = (const float*)d_in[38];
  const float* d_g1 = (const float*)d_in[39];
  const float* d_be1 = (const float*)d_in[40];
  const float* d_W2 = (const float*)d_in[41];
  const float* d_b2 = (const float*)d_in[42];

  char* wsb = (char*)d_ws;
  auto alloc = [&](size_t bytes) { char* p = wsb; wsb += (bytes + 255) & ~(size_t)255; return p; };

  _Float16* h16  = (_Float16*)alloc((size_t)MPAD * HD * 2);
  _Float16* Xl16 = (_Float16*)alloc((size_t)MPAD * HD * 2);
  _Float16* Xr16 = (_Float16*)alloc((size_t)MPAD * HD * 2);
  _Float16* WT   = (_Float16*)alloc((size_t)6 * HD * HD * 2);
  float* gsum    = (float*)alloc(256 * 4);
  float* qb      = (float*)alloc(SS * HD * 4);
  float* kb      = (float*)alloc(SS * HD * 4);
  float* vb      = (float*)alloc(SS * HD * 4);
  int* cnt       = (int*)alloc((size_t)NN * 4);
  int* rowptr    = (int*)alloc((size_t)(NN + 1) * 4);
  int* wptr      = (int*)alloc((size_t)NN * 4);
  int* csr_src   = (int*)alloc((size_t)ETOT * 4);
  int* gcnt      = (int*)alloc(4);

  float* out_q = (float*)d_out;        // [256]
  float* out_d = out_q + SS;           // [1]

  hipMemsetAsync(cnt, 0, (size_t)NN * sizeof(int), stream);
  hipMemsetAsync(gsum, 0, 256 * sizeof(float), stream);
  hipMemsetAsync(gcnt, 0, sizeof(int), stream);
  hipMemsetAsync(h16 + (size_t)NN * HD, 0, (size_t)(MPAD - NN) * HD * 2, stream);

  // CSR build
  k_count<<<(ETOT + 255) / 256, 256, 0, stream>>>(ei, cnt);
  k_scan<<<1, 1024, 0, stream>>>(cnt, rowptr, wptr);
  k_scatter<<<(ETOT + 255) / 256, 256, 0, stream>>>(ei, wptr, csr_src);

  // weights + pre-transform
  k_wconv<<<6 * 256, 256, 0, stream>>>(gat_Wl, gat_Wr, WT);
  k_pre<<<NN / 8, 256, 0, stream>>>(x, pre_W, pre_b, h16);

  // GAT layers
  dim3 ggrid(MPAD / 128, 4);
  for (int l = 0; l < NL; ++l) {
    k_gemm16<<<ggrid, 256, 0, stream>>>(h16, WT + (size_t)l * 2 * HD * HD, Xl16, Xr16);
    k_edgeagg<<<(NN + 3) / 4, 256, 0, stream>>>(Xl16, Xr16, gat_att + l * NH * CH,
                                                gat_b + l * HD, rowptr, csr_src, h16);
  }

  // global mean (sum + count)
  k_gsum<<<(NN + 255) / 256, 256, 0, stream>>>(h16, batch, gsum, gcnt);

  // fused tail
  k_tail1<<<SS, 256, 0, stream>>>(h16, sheet_idx, sheet_feat,
      geo_W1, geo_b1, geo_g1, geo_be1, geo_W2, geo_b2, geo_g2, geo_be2,
      ca_Wq, ca_bq, ca_Wk, ca_bk, ca_Wv, ca_bv, qb, kb, vb);
  k_tail2<<<SS, 256, 0, stream>>>(qb, kb, vb, ca_Wo, ca_bo, gsum, gcnt,
      q_W1, q_b1, q_g1, q_be1, q_W2, q_b2, q_g2, q_be2, q_W3, q_b3, out_q);

  // done predictor
  k_done<<<1, 128, 0, stream>>>(gsum, gcnt, d_W1, d_b1, d_g1, d_be1, d_W2, d_b2, out_d);
}

// Round 4
// 385.796 us; speedup vs baseline: 2.8742x; 1.2301x over previous
//
#include <hip/hip_runtime.h>
#include <hip/hip_bf16.h>
#include <stdint.h>

#define NN 30000
#define MPAD 30080
#define FI 16
#define EE 300000
#define ETOT (EE + NN)
#define HD 256
#define NH 8
#define CH 32
#define NL 3
#define SS 256
#define KS 128
#define NHC 4
#define HC 64
#define GSB 256
#define RPB 118

typedef _Float16 half8 __attribute__((ext_vector_type(8)));
typedef _Float16 half4v __attribute__((ext_vector_type(4)));
typedef float f32x4 __attribute__((ext_vector_type(4)));

// ---------------- weight transpose+convert ----------------
__global__ __launch_bounds__(256) void k_wconv(const float* __restrict__ Wl,
    const float* __restrict__ Wr, _Float16* __restrict__ WT)
{
  int m = blockIdx.x >> 8;
  int n = blockIdx.x & 255;
  int k = threadIdx.x;
  int l = m >> 1;
  const float* W = (m & 1) ? (Wr + (size_t)l * HD * HD) : (Wl + (size_t)l * HD * HD);
  WT[((size_t)m * HD + n) * HD + k] = (_Float16)W[k * HD + n];
}

// ---------------- pre-transform ----------------
__global__ __launch_bounds__(256) void k_pre(const float* __restrict__ x,
    const float* __restrict__ W, const float* __restrict__ b,
    _Float16* __restrict__ H16)
{
  __shared__ float Ws[FI][HD];
  __shared__ float xs[8][FI];
  int r0 = blockIdx.x * 8;
  int t = threadIdx.x;
  for (int i = t; i < FI * HD; i += 256) Ws[i >> 8][i & 255] = W[i];
  if (t < 8 * FI) xs[t >> 4][t & 15] = x[(size_t)(r0 + (t >> 4)) * FI + (t & 15)];
  __syncthreads();
  float bj = b[t];
  for (int r = 0; r < 8; ++r) {
    float acc = bj;
#pragma unroll
    for (int k = 0; k < FI; ++k) acc += xs[r][k] * Ws[k][t];
    H16[(size_t)(r0 + r) * HD + t] = (_Float16)acc;
  }
}

// ---------------- CSR build ----------------
__global__ __launch_bounds__(256) void k_count(const int* __restrict__ ei, int* __restrict__ cnt)
{
  int i = blockIdx.x * 256 + threadIdx.x;
  if (i >= ETOT) return;
  int dst = (i < EE) ? ei[EE + i] : (i - EE);
  atomicAdd(&cnt[dst], 1);
}

__global__ __launch_bounds__(1024) void k_scan(const int* __restrict__ cnt,
    int* __restrict__ rowptr, int* __restrict__ wptr)
{
  __shared__ int wsum[16];
  __shared__ int carry;
  int t = threadIdx.x, wid = t >> 6, lane = t & 63;
  if (t == 0) carry = 0;
  __syncthreads();
  for (int base = 0; base < NN; base += 1024) {
    int i = base + t;
    int v0 = (i < NN) ? cnt[i] : 0;
    int v = v0;
#pragma unroll
    for (int d = 1; d < 64; d <<= 1) {
      int u = __shfl_up(v, d);
      if (lane >= d) v += u;
    }
    if (lane == 63) wsum[wid] = v;
    __syncthreads();
    int carry_cur = carry;
    if (t < 16) {
      int s = wsum[t];
#pragma unroll
      for (int d = 1; d < 16; d <<= 1) {
        int u = __shfl_up(s, d);
        if (t >= d) s += u;
      }
      wsum[t] = s;
    }
    __syncthreads();
    int woff = (wid > 0) ? wsum[wid - 1] : 0;
    int excl = carry_cur + woff + v - v0;
    if (i < NN) { rowptr[i] = excl; wptr[i] = excl; }
    __syncthreads();
    if (t == 0) carry = carry_cur + wsum[15];
    __syncthreads();
  }
  if (t == 0) rowptr[NN] = carry;
}

__global__ __launch_bounds__(256) void k_scatter(const int* __restrict__ ei,
    int* __restrict__ wptr, int* __restrict__ csr_src)
{
  int i = blockIdx.x * 256 + threadIdx.x;
  if (i >= ETOT) return;
  int src = (i < EE) ? ei[i] : (i - EE);
  int dst = (i < EE) ? ei[EE + i] : (i - EE);
  int pos = atomicAdd(&wptr[dst], 1);
  csr_src[pos] = src;
}

// ---------------- fp16 MFMA GEMM ----------------
#define BK 64
__global__ __launch_bounds__(256) void k_gemm16(const _Float16* __restrict__ A,
    const _Float16* __restrict__ WT,
    _Float16* __restrict__ Xl, _Float16* __restrict__ Xr)
{
  __shared__ __align__(16) _Float16 As[128 * BK];
  __shared__ __align__(16) _Float16 Bs[128 * BK];
  int t = threadIdx.x;
  int w = t >> 6, lane = t & 63;
  int row0 = blockIdx.x * 128;
  int ct = blockIdx.y;
  const _Float16* Bmat = WT + (size_t)(ct >> 1) * HD * HD + (size_t)(ct & 1) * 128 * HD;
  _Float16* Out = (ct >> 1) ? Xr : Xl;
  int j0 = (ct & 1) * 128;

  f32x4 acc[4][4] = {};
  int wr = w >> 1, wc = w & 1;

  for (int k0 = 0; k0 < HD; k0 += BK) {
#pragma unroll
    for (int i = 0; i < 4; ++i) {
      int p = (i * 4 + w) * 64 + lane;
      int row = p >> 3, s = p & 7;
      int g = s ^ (row & 7);
      const _Float16* srcA = A + (size_t)(row0 + row) * HD + k0 + g * 8;
      __builtin_amdgcn_global_load_lds(
        (const __attribute__((address_space(1))) void*)srcA,
        (__attribute__((address_space(3))) void*)((char*)As + (i * 4 + w) * 1024),
        16, 0, 0);
      const _Float16* srcB = Bmat + (size_t)row * HD + k0 + g * 8;
      __builtin_amdgcn_global_load_lds(
        (const __attribute__((address_space(1))) void*)srcB,
        (__attribute__((address_space(3))) void*)((char*)Bs + (i * 4 + w) * 1024),
        16, 0, 0);
    }
    __syncthreads();
#pragma unroll
    for (int ks = 0; ks < 2; ++ks) {
      half8 af[4], bfr[4];
      int kslot = ks * 4 + (lane >> 4);
#pragma unroll
      for (int mi = 0; mi < 4; ++mi) {
        int rl = wr * 64 + mi * 16 + (lane & 15);
        int ps = kslot ^ (rl & 7);
        af[mi] = *(const half8*)((const char*)As + rl * 128 + ps * 16);
      }
#pragma unroll
      for (int ni = 0; ni < 4; ++ni) {
        int nl = wc * 64 + ni * 16 + (lane & 15);
        int ps = kslot ^ (nl & 7);
        bfr[ni] = *(const half8*)((const char*)Bs + nl * 128 + ps * 16);
      }
#pragma unroll
      for (int mi = 0; mi < 4; ++mi)
#pragma unroll
        for (int ni = 0; ni < 4; ++ni)
          acc[mi][ni] = __builtin_amdgcn_mfma_f32_16x16x32_f16(af[mi], bfr[ni], acc[mi][ni], 0, 0, 0);
    }
    __syncthreads();
  }
  int crow = (lane >> 4) * 4;
  int ccol = lane & 15;
#pragma unroll
  for (int mi = 0; mi < 4; ++mi)
#pragma unroll
    for (int ni = 0; ni < 4; ++ni) {
      size_t base_r = row0 + wr * 64 + mi * 16 + crow;
      int c = j0 + wc * 64 + ni * 16 + ccol;
#pragma unroll
      for (int r = 0; r < 4; ++r)
        Out[(base_r + r) * HD + c] = (_Float16)acc[mi][ni][r];
    }
}

// ---------------- fused edge + online-softmax agg (defer-max) ----------------
__global__ __launch_bounds__(256) void k_edgeagg(const _Float16* __restrict__ Xl,
    const _Float16* __restrict__ Xr, const float* __restrict__ attw,
    const float* __restrict__ bias, const int* __restrict__ rowptr,
    const int* __restrict__ csr_src, _Float16* __restrict__ H16)
{
  int node = blockIdx.x * 4 + (threadIdx.x >> 6);
  int lane = threadIdx.x & 63;
  if (node >= NN) return;
  int st = rowptr[node], en = rowptr[node + 1];
  int c = lane * 4;
  half4v xrv = *(const half4v*)(Xr + (size_t)node * HD + c);
  float r0 = (float)xrv[0], r1 = (float)xrv[1], r2 = (float)xrv[2], r3 = (float)xrv[3];
  float4 wv = *(const float4*)(attw + c);
  float mh = -1e30f, dsum = 0.f;
  float a0 = 0.f, a1 = 0.f, a2 = 0.f, a3 = 0.f;

  half4v v0 = *(const half4v*)(Xl + (size_t)csr_src[st] * HD + c);
  half4v v1 = {};
  if (st + 1 < en) v1 = *(const half4v*)(Xl + (size_t)csr_src[st + 1] * HD + c);

  for (int i = st; i < en; i += 2) {
    bool has1 = (i + 1 < en);
    half4v p0 = {}, p1 = {};
    if (i + 2 < en) p0 = *(const half4v*)(Xl + (size_t)csr_src[i + 2] * HD + c);
    if (i + 3 < en) p1 = *(const half4v*)(Xl + (size_t)csr_src[i + 3] * HD + c);

    float x00 = (float)v0[0], x01 = (float)v0[1], x02 = (float)v0[2], x03 = (float)v0[3];
    float x10 = (float)v1[0], x11 = (float)v1[1], x12 = (float)v1[2], x13 = (float)v1[3];

    float m, e0 = 0.f, e1 = 0.f;
    m = x00 + r0; m = (m > 0.f) ? m : 0.2f * m; e0 += wv.x * m;
    m = x01 + r1; m = (m > 0.f) ? m : 0.2f * m; e0 += wv.y * m;
    m = x02 + r2; m = (m > 0.f) ? m : 0.2f * m; e0 += wv.z * m;
    m = x03 + r3; m = (m > 0.f) ? m : 0.2f * m; e0 += wv.w * m;
    m = x10 + r0; m = (m > 0.f) ? m : 0.2f * m; e1 += wv.x * m;
    m = x11 + r1; m = (m > 0.f) ? m : 0.2f * m; e1 += wv.y * m;
    m = x12 + r2; m = (m > 0.f) ? m : 0.2f * m; e1 += wv.z * m;
    m = x13 + r3; m = (m > 0.f) ? m : 0.2f * m; e1 += wv.w * m;
    e0 += __shfl_xor(e0, 1); e1 += __shfl_xor(e1, 1);
    e0 += __shfl_xor(e0, 2); e1 += __shfl_xor(e1, 2);
    e0 += __shfl_xor(e0, 4); e1 += __shfl_xor(e1, 4);
    if (!has1) e1 = -1e30f;

    // defer-max: only rescale when the running max grows by > 8
    float pmax = fmaxf(e0, e1);
    if (__any(pmax > mh + 8.f)) {
      float nm = fmaxf(mh, pmax);
      float sc = __expf(mh - nm);
      a0 *= sc; a1 *= sc; a2 *= sc; a3 *= sc; dsum *= sc;
      mh = nm;
    }
    float pw0 = __expf(e0 - mh);
    float pw1 = __expf(e1 - mh);
    a0 += pw0 * x00 + pw1 * x10;
    a1 += pw0 * x01 + pw1 * x11;
    a2 += pw0 * x02 + pw1 * x12;
    a3 += pw0 * x03 + pw1 * x13;
    dsum += pw0 + pw1;
    v0 = p0; v1 = p1;
  }
  float inv = 1.f / (dsum + 1e-16f);
  float4 bb = *(const float4*)(bias + c);
  float o0 = a0 * inv + bb.x, o1 = a1 * inv + bb.y;
  float o2 = a2 * inv + bb.z, o3 = a3 * inv + bb.w;
  o0 = (o0 > 0.f) ? o0 : expm1f(o0);
  o1 = (o1 > 0.f) ? o1 : expm1f(o1);
  o2 = (o2 > 0.f) ? o2 : expm1f(o2);
  o3 = (o3 > 0.f) ? o3 : expm1f(o3);
  half4v h4;
  h4[0] = (_Float16)o0; h4[1] = (_Float16)o1; h4[2] = (_Float16)o2; h4[3] = (_Float16)o3;
  *(half4v*)(H16 + (size_t)node * HD + c) = h4;
}

// ---------------- global sum: per-block partials, no atomics ----------------
__global__ __launch_bounds__(256) void k_gsum(const _Float16* __restrict__ H,
    const int* __restrict__ batch, float* __restrict__ gpart, int* __restrict__ gcnt)
{
  __shared__ float flagf[RPB];
  __shared__ int scount;
  int b = blockIdx.x, t = threadIdx.x;
  int r0 = b * RPB;
  int nr = NN - r0; if (nr > RPB) nr = RPB; if (nr < 0) nr = 0;
  if (t == 0) scount = 0;
  __syncthreads();
  if (t < nr) {
    int ok = (batch[r0 + t] == 0) ? 1 : 0;
    flagf[t] = (float)ok;
    if (ok) atomicAdd(&scount, 1);
  }
  __syncthreads();
  float a0 = 0.f, a1 = 0.f, a2 = 0.f, a3 = 0.f;
  const _Float16* Hp = H + (size_t)r0 * HD + t;
  int r = 0;
  for (; r + 4 <= nr; r += 4) {
    float v0 = (float)Hp[(size_t)(r + 0) * HD];
    float v1 = (float)Hp[(size_t)(r + 1) * HD];
    float v2 = (float)Hp[(size_t)(r + 2) * HD];
    float v3 = (float)Hp[(size_t)(r + 3) * HD];
    a0 += v0 * flagf[r + 0]; a1 += v1 * flagf[r + 1];
    a2 += v2 * flagf[r + 2]; a3 += v3 * flagf[r + 3];
  }
  for (; r < nr; ++r) a0 += (float)Hp[(size_t)r * HD] * flagf[r];
  gpart[(size_t)b * HD + t] = (a0 + a1) + (a2 + a3);
  if (t == 0 && scount) atomicAdd(gcnt, scount);
}

__global__ __launch_bounds__(256) void k_gfin(const float* __restrict__ gpart,
    const int* __restrict__ gcnt, float* __restrict__ gvec)
{
  int t = threadIdx.x;
  float a0 = 0.f, a1 = 0.f, a2 = 0.f, a3 = 0.f;
  for (int b = 0; b < GSB; b += 4) {
    a0 += gpart[(size_t)b * HD + t];
    a1 += gpart[(size_t)(b + 1) * HD + t];
    a2 += gpart[(size_t)(b + 2) * HD + t];
    a3 += gpart[(size_t)(b + 3) * HD + t];
  }
  gvec[t] = ((a0 + a1) + (a2 + a3)) / (float)(*gcnt);
}

// ---------------- LayerNorm helper for 1024-thread blocks ----------------
// `a` valid for t < n; returns LN(+relu) value for t < n. red has >= n floats.
__device__ __forceinline__ float ln1024(float a, int t, float* red,
    const float* __restrict__ G, const float* __restrict__ Be, int n, bool relu)
{
  if (t < n) red[t] = a;
  __syncthreads();
  for (int s = n >> 1; s > 0; s >>= 1) { if (t < s) red[t] += red[t + s]; __syncthreads(); }
  float mu = red[0] / n;
  __syncthreads();
  float d = a - mu;
  if (t < n) red[t] = d * d;
  __syncthreads();
  for (int s = n >> 1; s > 0; s >>= 1) { if (t < s) red[t] += red[t + s]; __syncthreads(); }
  float var = red[0] / n;
  __syncthreads();
  float o = 0.f;
  if (t < n) {
    o = d * rsqrtf(var + 1e-5f) * G[t] + Be[t];
    if (relu) o = fmaxf(o, 0.f);
  }
  return o;
}

// ---------------- tail1: sheet pool + geo encoder + Q/K/V (1024 thr) ----------------
__global__ __launch_bounds__(1024) void k_tail1(const _Float16* __restrict__ h16,
    const int* __restrict__ sheet_idx, const float* __restrict__ sheet_feat,
    const float* __restrict__ geo_W1, const float* __restrict__ geo_b1,
    const float* __restrict__ geo_g1, const float* __restrict__ geo_be1,
    const float* __restrict__ geo_W2, const float* __restrict__ geo_b2,
    const float* __restrict__ geo_g2, const float* __restrict__ geo_be2,
    const float* __restrict__ ca_Wq, const float* __restrict__ ca_bq,
    const float* __restrict__ ca_Wk, const float* __restrict__ ca_bk,
    const float* __restrict__ ca_Wv, const float* __restrict__ ca_bv,
    float* __restrict__ qb, float* __restrict__ kb, float* __restrict__ vb)
{
  __shared__ float sh[HD];
  __shared__ float g1v[HD];
  __shared__ float g2v[HD];
  __shared__ float xf[FI];
  __shared__ float red4[1024];
  __shared__ float red[HD];
  int s = blockIdx.x, t = threadIdx.x;
  int j = t & 255, kq = t >> 8;

  // sheet pool: 4 groups x 32 rows
  float p = 0.f;
  {
    int rr0 = kq * 32;
#pragma unroll 4
    for (int r = rr0; r < rr0 + 32; ++r) {
      int n = sheet_idx[s * KS + r];
      p += (float)h16[(size_t)n * HD + j];
    }
  }
  red4[t] = p;
  if (t >= 256 && t < 256 + FI) xf[t - 256] = sheet_feat[s * FI + (t - 256)];
  __syncthreads();
  if (kq == 0) sh[j] = (red4[j] + red4[256 + j] + red4[512 + j] + red4[768 + j]) * (1.f / KS);

  // geo1 (16-dim input, kq==0 computes)
  float a = 0.f;
  if (kq == 0) {
    a = geo_b1[j];
#pragma unroll
    for (int k = 0; k < FI; ++k) a += xf[k] * geo_W1[k * HD + j];
  }
  float g1 = ln1024(a, t, red, geo_g1, geo_be1, HD, true);
  if (t < 256) g1v[t] = g1;
  __syncthreads();

  // geo2: k split 4 ways
  float p2 = 0.f;
  for (int k = kq * 64; k < kq * 64 + 64; ++k) p2 += g1v[k] * geo_W2[(size_t)k * HD + j];
  red4[t] = p2;
  __syncthreads();
  float a2 = 0.f;
  if (kq == 0) a2 = geo_b2[j] + red4[j] + red4[256 + j] + red4[512 + j] + red4[768 + j];
  float g2 = ln1024(a2, t, red, geo_g2, geo_be2, HD, true);
  if (t < 256) g2v[t] = g2;
  __syncthreads();

  // qkv: k split 4 ways
  float pq = 0.f, pk = 0.f, pv = 0.f;
  for (int k = kq * 64; k < kq * 64 + 64; ++k) {
    float shk = sh[k], g2k = g2v[k];
    pq += shk * ca_Wq[(size_t)k * HD + j];
    pk += g2k * ca_Wk[(size_t)k * HD + j];
    pv += g2k * ca_Wv[(size_t)k * HD + j];
  }
  red4[t] = pq; __syncthreads();
  if (kq == 0) qb[(size_t)s * HD + j] = ca_bq[j] + red4[j] + red4[256 + j] + red4[512 + j] + red4[768 + j];
  __syncthreads();
  red4[t] = pk; __syncthreads();
  if (kq == 0) kb[(size_t)s * HD + j] = ca_bk[j] + red4[j] + red4[256 + j] + red4[512 + j] + red4[768 + j];
  __syncthreads();
  red4[t] = pv; __syncthreads();
  if (kq == 0) vb[(size_t)s * HD + j] = ca_bv[j] + red4[j] + red4[256 + j] + red4[512 + j] + red4[768 + j];
}

// ---------------- tail2: cross-attn + q-MLP (+done in block SS), 1024 thr ----------------
__global__ __launch_bounds__(1024) void k_tail2(const float* __restrict__ qb,
    const float* __restrict__ kb, const float* __restrict__ vb,
    const float* __restrict__ ca_Wo, const float* __restrict__ ca_bo,
    const float* __restrict__ gvec,
    const float* __restrict__ q_W1, const float* __restrict__ q_b1,
    const float* __restrict__ q_g1, const float* __restrict__ q_be1,
    const float* __restrict__ q_W2, const float* __restrict__ q_b2,
    const float* __restrict__ q_g2, const float* __restrict__ q_be2,
    const float* __restrict__ q_W3, const float* __restrict__ q_b3,
    const float* __restrict__ d_W1, const float* __restrict__ d_b1,
    const float* __restrict__ d_g1, const float* __restrict__ d_be1,
    const float* __restrict__ d_W2, const float* __restrict__ d_b2,
    float* __restrict__ out_q, float* __restrict__ out_d)
{
  __shared__ float qv[HD];
  __shared__ float gv[HD];
  __shared__ float att_s[NHC * SS];
  __shared__ float pvs[HD];
  __shared__ float fu[HD];
  __shared__ float hq1[HD];
  __shared__ float red4[1024];
  __shared__ float red[HD];
  int blk = blockIdx.x, t = threadIdx.x;

  if (blk == SS) {
    // ---- done predictor ----
    int j2 = t & 127, k8 = t >> 7;
    if (t < 256) qv[t] = gvec[t];
    __syncthreads();
    float p = 0.f;
    for (int k = k8 * 32; k < k8 * 32 + 32; ++k) p += qv[k] * d_W1[(size_t)k * 128 + j2];
    red4[t] = p;
    __syncthreads();
    float a = 0.f;
    if (k8 == 0) {
      a = d_b1[j2];
#pragma unroll
      for (int g = 0; g < 8; ++g) a += red4[g * 128 + j2];
    }
    float hd = ln1024(a, t, red, d_g1, d_be1, 128, true);
    if (t < 128) red[t] = hd * d_W2[t];
    __syncthreads();
    for (int s2 = 64; s2 > 0; s2 >>= 1) { if (t < s2) red[t] += red[t + s2]; __syncthreads(); }
    if (t == 0) out_d[0] = red[0] + d_b2[0];
    return;
  }

  int j = t & 255, kq = t >> 8;
  if (t < 256) { qv[t] = qb[(size_t)blk * HD + t]; gv[t] = gvec[t]; }
  __syncthreads();

  // scores: thread (kq=head, j=key)
  float sc = 0.f;
  {
    const float4* kr4 = (const float4*)(kb + (size_t)j * HD + kq * HC);
    const float4* q4 = (const float4*)(qv + kq * HC);
#pragma unroll
    for (int d = 0; d < 16; ++d) {
      float4 kk = kr4[d], qq = q4[d];
      sc += qq.x * kk.x + qq.y * kk.y + qq.z * kk.z + qq.w * kk.w;
    }
    sc *= 0.125f;
  }
  int g0 = kq * 256;
  red4[g0 + j] = sc;
  __syncthreads();
  for (int s2 = 128; s2 > 0; s2 >>= 1) { if (j < s2) red4[g0 + j] = fmaxf(red4[g0 + j], red4[g0 + j + s2]); __syncthreads(); }
  float mx = red4[g0];
  __syncthreads();
  float ev = __expf(sc - mx);
  red4[g0 + j] = ev;
  __syncthreads();
  for (int s2 = 128; s2 > 0; s2 >>= 1) { if (j < s2) red4[g0 + j] += red4[g0 + j + s2]; __syncthreads(); }
  att_s[g0 + j] = ev / red4[g0];
  __syncthreads();

  // pv: channel j, k split 4 ways over keys
  int hj = j >> 6;
  float p = 0.f;
  for (int k = kq * 64; k < kq * 64 + 64; ++k) p += att_s[hj * 256 + k] * vb[(size_t)k * HD + j];
  red4[t] = p;
  __syncthreads();
  if (kq == 0) pvs[j] = red4[j] + red4[256 + j] + red4[512 + j] + red4[768 + j];
  __syncthreads();

  // fused = pv @ Wo + bo
  float p2 = 0.f;
  for (int k = kq * 64; k < kq * 64 + 64; ++k) p2 += pvs[k] * ca_Wo[(size_t)k * HD + j];
  red4[t] = p2;
  __syncthreads();
  if (kq == 0) fu[j] = ca_bo[j] + red4[j] + red4[256 + j] + red4[512 + j] + red4[768 + j];
  __syncthreads();

  // hq1 = relu(LN([fu|gv] @ qW1 + b1)); 512-dim input split 4x128
  float p3 = 0.f;
  for (int k = kq * 128; k < kq * 128 + 128; ++k) {
    float in = (k < 256) ? fu[k] : gv[k - 256];
    p3 += in * q_W1[(size_t)k * HD + j];
  }
  red4[t] = p3;
  __syncthreads();
  float a1 = 0.f;
  if (kq == 0) a1 = q_b1[j] + red4[j] + red4[256 + j] + red4[512 + j] + red4[768 + j];
  float h1 = ln1024(a1, t, red, q_g1, q_be1, HD, true);
  if (t < 256) hq1[t] = h1;
  __syncthreads();

  // hq2 = relu(LN(hq1 @ qW2 + b2)); 128 outputs, k split 8x32
  int j2 = t & 127, k8 = t >> 7;
  float p4 = 0.f;
  for (int k = k8 * 32; k < k8 * 32 + 32; ++k) p4 += hq1[k] * q_W2[(size_t)k * 128 + j2];
  red4[t] = p4;
  __syncthreads();
  float a2 = 0.f;
  if (k8 == 0) {
    a2 = q_b2[j2];
#pragma unroll
    for (int g = 0; g < 8; ++g) a2 += red4[g * 128 + j2];
  }
  float h2 = ln1024(a2, t, red, q_g2, q_be2, 128, true);
  if (t < 128) red[t] = h2 * q_W3[t];
  __syncthreads();
  for (int s2 = 64; s2 > 0; s2 >>= 1) { if (t < s2) red[t] += red[t + s2]; __syncthreads(); }
  if (t == 0) out_q[blk] = red[0] + q_b3[0];
}

// =====================================================================
extern "C" void kernel_launch(void* const* d_in, const int* in_sizes, int n_in,
                              void* d_out, int out_size, void* d_ws, size_t ws_size,
                              hipStream_t stream) {
  const float* x      = (const float*)d_in[0];
  const int*   ei     = (const int*)d_in[1];
  const int*   batch  = (const int*)d_in[2];
  const int*   sheet_idx = (const int*)d_in[3];
  const float* sheet_feat = (const float*)d_in[4];
  const float* pre_W  = (const float*)d_in[5];
  const float* pre_b  = (const float*)d_in[6];
  const float* gat_Wl = (const float*)d_in[7];
  const float* gat_Wr = (const float*)d_in[8];
  const float* gat_att = (const float*)d_in[9];
  const float* gat_b  = (const float*)d_in[10];
  const float* geo_W1 = (const float*)d_in[11];
  const float* geo_b1 = (const float*)d_in[12];
  const float* geo_g1 = (const float*)d_in[13];
  const float* geo_be1 = (const float*)d_in[14];
  const float* geo_W2 = (const float*)d_in[15];
  const float* geo_b2 = (const float*)d_in[16];
  const float* geo_g2 = (const float*)d_in[17];
  const float* geo_be2 = (const float*)d_in[18];
  const float* ca_Wq = (const float*)d_in[19];
  const float* ca_bq = (const float*)d_in[20];
  const float* ca_Wk = (const float*)d_in[21];
  const float* ca_bk = (const float*)d_in[22];
  const float* ca_Wv = (const float*)d_in[23];
  const float* ca_bv = (const float*)d_in[24];
  const float* ca_Wo = (const float*)d_in[25];
  const float* ca_bo = (const float*)d_in[26];
  const float* q_W1 = (const float*)d_in[27];
  const float* q_b1 = (const float*)d_in[28];
  const float* q_g1 = (const float*)d_in[29];
  const float* q_be1 = (const float*)d_in[30];
  const float* q_W2 = (const float*)d_in[31];
  const float* q_b2 = (const float*)d_in[32];
  const float* q_g2 = (const float*)d_in[33];
  const float* q_be2 = (const float*)d_in[34];
  const float* q_W3 = (const float*)d_in[35];
  const float* q_b3 = (const float*)d_in[36];
  const float* d_W1 = (const float*)d_in[37];
  const float* d_b1 = (const float*)d_in[38];
  const float* d_g1 = (const float*)d_in[39];
  const float* d_be1 = (const float*)d_in[40];
  const float* d_W2 = (const float*)d_in[41];
  const float* d_b2 = (const float*)d_in[42];

  char* wsb = (char*)d_ws;
  auto alloc = [&](size_t bytes) { char* p = wsb; wsb += (bytes + 255) & ~(size_t)255; return p; };

  _Float16* h16  = (_Float16*)alloc((size_t)MPAD * HD * 2);
  _Float16* Xl16 = (_Float16*)alloc((size_t)MPAD * HD * 2);
  _Float16* Xr16 = (_Float16*)alloc((size_t)MPAD * HD * 2);
  _Float16* WT   = (_Float16*)alloc((size_t)6 * HD * HD * 2);
  float* gpart   = (float*)alloc((size_t)GSB * HD * 4);
  float* gvec    = (float*)alloc(256 * 4);
  float* qb      = (float*)alloc(SS * HD * 4);
  float* kb      = (float*)alloc(SS * HD * 4);
  float* vb      = (float*)alloc(SS * HD * 4);
  int* cnt       = (int*)alloc((size_t)NN * 4);
  int* rowptr    = (int*)alloc((size_t)(NN + 1) * 4);
  int* wptr      = (int*)alloc((size_t)NN * 4);
  int* csr_src   = (int*)alloc((size_t)ETOT * 4);
  int* gcnt      = (int*)alloc(4);

  float* out_q = (float*)d_out;        // [256]
  float* out_d = out_q + SS;           // [1]

  hipMemsetAsync(cnt, 0, (size_t)NN * sizeof(int), stream);
  hipMemsetAsync(gcnt, 0, sizeof(int), stream);
  hipMemsetAsync(h16 + (size_t)NN * HD, 0, (size_t)(MPAD - NN) * HD * 2, stream);

  // CSR build
  k_count<<<(ETOT + 255) / 256, 256, 0, stream>>>(ei, cnt);
  k_scan<<<1, 1024, 0, stream>>>(cnt, rowptr, wptr);
  k_scatter<<<(ETOT + 255) / 256, 256, 0, stream>>>(ei, wptr, csr_src);

  // weights + pre-transform
  k_wconv<<<6 * 256, 256, 0, stream>>>(gat_Wl, gat_Wr, WT);
  k_pre<<<NN / 8, 256, 0, stream>>>(x, pre_W, pre_b, h16);

  // GAT layers
  dim3 ggrid(MPAD / 128, 4);
  for (int l = 0; l < NL; ++l) {
    k_gemm16<<<ggrid, 256, 0, stream>>>(h16, WT + (size_t)l * 2 * HD * HD, Xl16, Xr16);
    k_edgeagg<<<(NN + 3) / 4, 256, 0, stream>>>(Xl16, Xr16, gat_att + l * NH * CH,
                                                gat_b + l * HD, rowptr, csr_src, h16);
  }

  // global mean
  k_gsum<<<GSB, 256, 0, stream>>>(h16, batch, gpart, gcnt);
  k_gfin<<<1, 256, 0, stream>>>(gpart, gcnt, gvec);

  // fused tail
  k_tail1<<<SS, 1024, 0, stream>>>(h16, sheet_idx, sheet_feat,
      geo_W1, geo_b1, geo_g1, geo_be1, geo_W2, geo_b2, geo_g2, geo_be2,
      ca_Wq, ca_bq, ca_Wk, ca_bk, ca_Wv, ca_bv, qb, kb, vb);
  k_tail2<<<SS + 1, 1024, 0, stream>>>(qb, kb, vb, ca_Wo, ca_bo, gvec,
      q_W1, q_b1, q_g1, q_be1, q_W2, q_b2, q_g2, q_be2, q_W3, q_b3,
      d_W1, d_b1, d_g1, d_be1, d_W2, d_b2, out_q, out_d);
}